// Round 1
// baseline (1584.157 us; speedup 1.0000x reference)
//
#include <hip/hip_runtime.h>
#include <stdint.h>

// ---------------- problem constants ----------------
constexpr int N_   = 20000;
constexpr int E_   = 160000;
constexpr int C_   = 64;
constexpr int K_   = 2000;
constexpr int EV_  = 32000;
constexpr int EALL_ = E_ + EV_;          // 192000
constexpr int CSH_ = 576;                // C*SH

// ---------------- workspace layout (bytes) ----------------
constexpr size_t OFF_HLOCAL = 0;                  // N*C f32       5,120,000
constexpr size_t OFF_AGG    = 5120000;            // N*C f32       5,120,000
constexpr size_t OFF_DEG    = 10240000;           // N f32            80,000
constexpr size_t OFF_KEY    = 10320000;           // N u64           160,000
constexpr size_t OFF_SCORE  = 10480000;           // N f32            80,000
constexpr size_t OFF_SELF   = 10560000;           // N i32            80,000
constexpr size_t OFF_N2M    = 10640000;           // N i32            80,000
constexpr size_t OFF_MIDX   = 10720000;           // K i32             8,000
constexpr size_t OFF_HM     = 10728000;           // K*C f32         512,000
constexpr size_t OFF_POSM   = 11240000;           // K*3 f32          24,000
constexpr size_t OFF_Q      = 11264000;           // K*16 f32        128,000
constexpr size_t OFF_KBUF   = 11392000;           // K*16 f32        128,000
constexpr size_t OFF_EXIST  = 11520000;           // K*K u8        4,000,000
constexpr size_t OFF_SRCA   = 15520000;           // EALL i32        768,000
constexpr size_t OFF_DSTA   = 16288000;           // EALL i32        768,000
constexpr size_t OFF_MASKA  = 17056000;           // EALL f32        768,000
constexpr size_t OFF_AGGM   = 17824000;           // K*C f32         512,000
constexpr size_t OFF_DEGM   = 18336000;           // K f32             8,000
constexpr size_t OFF_W0     = 18344000;           // 576 f32           2,304
constexpr size_t OFF_W0NZ   = 18346304;           // i32
constexpr size_t OFF_STATE  = 18346400;           // RState            1,048
constexpr size_t OFF_CAND   = 18348000;           // K*K u64      32,000,000
// total ~50.35 MB

struct RState {
    unsigned long long prefix;
    int R;
    unsigned int cand_count;
    unsigned int sel_count;
    unsigned int pad;
    unsigned int hist[256];
};

// ---------------- w0 = relu(b1) @ fc_w2 + b2 (edge-independent weight when env==0) ----------------
__global__ void k_w0(const float* __restrict__ fc_b1, const float* __restrict__ fc_w2,
                     const float* __restrict__ fc_b2, float* __restrict__ w0, int* __restrict__ w0nz)
{
    __shared__ float hid0[64];
    __shared__ int nz;
    int tid = threadIdx.x;
    if (tid == 0) nz = 0;
    if (tid < 64) hid0[tid] = fmaxf(fc_b1[tid], 0.0f);
    __syncthreads();
    if (tid < CSH_) {
        float acc = fc_b2[tid];
        for (int k = 0; k < 64; k++) acc += hid0[k] * fc_w2[k * CSH_ + tid];
        w0[tid] = acc;
        if (acc != 0.0f) atomicOr(&nz, 1);
    }
    __syncthreads();
    if (tid == 0) *w0nz = nz;
}

// ---------------- generic edge conv: one wave per edge ----------------
__global__ __launch_bounds__(256) void k_conv(
    int n_edges,
    const int* __restrict__ src, const int* __restrict__ dst,
    const float* __restrict__ mask,       // nullptr -> all ones
    const float* __restrict__ hn,         // node features (n_nodes x 64)
    const float* __restrict__ posn,       // node positions (n_nodes x 3)
    const float* __restrict__ fc_w1, const float* __restrict__ fc_b1,
    const float* __restrict__ fc_w2, const float* __restrict__ fc_b2,
    const float* __restrict__ lin_w,
    const float* __restrict__ w0, const int* __restrict__ w0nz,
    float* __restrict__ agg, float* __restrict__ deg)
{
    const int wid  = threadIdx.x >> 6;
    const int lane = threadIdx.x & 63;
    const int e = blockIdx.x * 4 + wid;
    __shared__ float s_hid[4][64];
    __shared__ float s_tp[4][CSH_];

    bool valid = e < n_edges;
    int s_i = 0, d_i = 0; float msk = 0.0f;
    if (valid) {
        s_i = src[e]; d_i = dst[e];
        msk = mask ? mask[e] : 1.0f;
    }
    bool active = valid && (msk != 0.0f);

    float vx = 0.f, vy = 0.f, vz = 0.f;
    if (active) {
        vx = posn[s_i*3+0] - posn[d_i*3+0];
        vy = posn[s_i*3+1] - posn[d_i*3+1];
        vz = posn[s_i*3+2] - posn[d_i*3+2];
    }
    float r = sqrtf(vx*vx + vy*vy + vz*vz + 1e-12f);
    float invr = 1.0f / r;
    float x = vx*invr, y = vy*invr, z = vz*invr;
    const float s3 = 1.7320508075688772f, s15 = 3.872983346207417f, s5 = 2.23606797749979f;
    float sh[9];
    sh[0] = 1.0f; sh[1] = s3*x; sh[2] = s3*y; sh[3] = s3*z;
    sh[4] = s15*x*y; sh[5] = s15*y*z; sh[6] = 0.5f*s5*(3.0f*z*z - 1.0f);
    sh[7] = s15*x*z; sh[8] = 0.5f*s15*(x*x - y*y);

    float u = r * 0.2f; u = u > 1.0f ? 1.0f : u;
    float u2 = u*u, u6 = u2*u2*u2, u7 = u6*u, u8 = u7*u;
    float env = 1.0f - 28.0f*u6 + 48.0f*u7 - 21.0f*u8;
    float rc = r > 1e-9f ? r : 1e-9f;
    const float bpref = 0.6324555320336759f;      // sqrt(2/5)
    const float PIov5 = 0.6283185307179586f;
    float ef[8];
    #pragma unroll
    for (int n = 0; n < 8; n++)
        ef[n] = bpref * sinf(PIov5 * r * (float)(n + 1)) / rc * env;

    int w0flag = *w0nz;
    bool cw = (env == 0.0f);                   // ef==0 -> w == w0 exactly
    bool heavy = active && !(cw && w0flag == 0);

    if (heavy && !cw) {
        float acc = fc_b1[lane];
        #pragma unroll
        for (int n = 0; n < 8; n++) acc += ef[n] * fc_w1[n*64 + lane];
        s_hid[wid][lane] = fmaxf(acc, 0.0f);
    }
    __syncthreads();
    if (heavy) {
        float w[9];
        if (cw) {
            #pragma unroll
            for (int t = 0; t < 9; t++) w[t] = w0[t*64 + lane];
        } else {
            #pragma unroll
            for (int t = 0; t < 9; t++) w[t] = fc_b2[t*64 + lane];
            for (int k = 0; k < 64; k++) {
                float hk = s_hid[wid][k];
                #pragma unroll
                for (int t = 0; t < 9; t++)
                    w[t] += hk * fc_w2[k*CSH_ + t*64 + lane];
            }
        }
        #pragma unroll
        for (int t = 0; t < 9; t++) {
            int j = t*64 + lane;
            int c = j / 9;
            int si = j - c*9;
            float hd = hn[d_i*64 + c];
            s_tp[wid][j] = hd * sh[si] * w[t];
        }
    }
    __syncthreads();
    if (heavy) {
        float msg = 0.0f;
        for (int j = 0; j < CSH_; j++) msg += s_tp[wid][j] * lin_w[j*64 + lane];
        atomicAdd(&agg[s_i*64 + lane], msg * msk);
    }
    if (active && lane == 0) atomicAdd(&deg[s_i], msk);
}

// ---------------- h_local = h + agg/max(deg,1) ----------------
__global__ void k_hlocal(const float* __restrict__ h, const float* __restrict__ agg,
                         const float* __restrict__ deg, float* __restrict__ h_local)
{
    int idx = blockIdx.x * 256 + threadIdx.x;
    if (idx < N_ * C_) {
        float d = deg[idx >> 6];
        h_local[idx] = h[idx] + agg[idx] / fmaxf(d, 1.0f);
    }
}

// ---------------- per-node score + composite sort key ----------------
__global__ __launch_bounds__(256) void k_score(const float* __restrict__ h_local,
    const float* __restrict__ ms_w1, const float* __restrict__ ms_b1,
    const float* __restrict__ ms_w2, const float* __restrict__ ms_b2,
    float* __restrict__ score, unsigned long long* __restrict__ key)
{
    int wid = threadIdx.x >> 6, lane = threadIdx.x & 63;
    int n = blockIdx.x * 4 + wid;
    if (n >= N_) return;
    float acc = ms_b1[lane];
    #pragma unroll
    for (int i = 0; i < 16; i++) acc += h_local[n*64 + i] * ms_w1[i*64 + lane];
    acc = fmaxf(acc, 0.0f);
    float part = acc * ms_w2[lane];
    #pragma unroll
    for (int off = 32; off > 0; off >>= 1) part += __shfl_xor(part, off);
    if (lane == 0) {
        float s = part + ms_b2[0];
        float sc = 1.0f / (1.0f + expf(-s));
        score[n] = sc;
        key[n] = ((unsigned long long)__float_as_uint(sc) << 32)
               | (unsigned long long)(0xFFFFFFFFu - (unsigned)n);
    }
}

// ---------------- exact top-K by rank counting (unique keys) ----------------
__global__ void k_rank(const unsigned long long* __restrict__ key,
                       const float* __restrict__ score,
                       int* __restrict__ selflag, float* __restrict__ m_out)
{
    __shared__ unsigned long long tile[256];
    int i = blockIdx.x * 256 + threadIdx.x;
    unsigned long long my = (i < N_) ? key[i] : 0ull;
    int cnt = 0;
    for (int t0 = 0; t0 < N_; t0 += 256) {
        int idx = t0 + threadIdx.x;
        tile[threadIdx.x] = (idx < N_) ? key[idx] : 0ull;
        __syncthreads();
        #pragma unroll 8
        for (int j = 0; j < 256; j++) cnt += (tile[j] > my) ? 1 : 0;
        __syncthreads();
    }
    if (i < N_) {
        int sel = (cnt < K_) ? 1 : 0;
        selflag[i] = sel;
        m_out[i] = sel ? score[i] : 0.0f;
    }
}

// ---------------- single-block prefix scan: node2m + master_idx ----------------
__global__ void k_scan(const int* __restrict__ selflag, int* __restrict__ node2m,
                       int* __restrict__ midx)
{
    __shared__ int ssum[1024];
    int tid = threadIdx.x;
    int start = tid * 20;
    int c = 0;
    for (int k = 0; k < 20; k++) { int idx = start + k; if (idx < N_) c += selflag[idx]; }
    ssum[tid] = c;
    __syncthreads();
    for (int off = 1; off < 1024; off <<= 1) {
        int v = (tid >= off) ? ssum[tid - off] : 0;
        __syncthreads();
        ssum[tid] += v;
        __syncthreads();
    }
    int run = ssum[tid] - c;
    for (int k = 0; k < 20; k++) {
        int idx = start + k;
        if (idx < N_) {
            if (selflag[idx]) { node2m[idx] = run; midx[run] = idx; run++; }
            else node2m[idx] = -1;
        }
    }
}

// ---------------- gather master nodes + q/k projections ----------------
__global__ void k_master(const int* __restrict__ midx, const float* __restrict__ h_local,
    const float* __restrict__ pos, const float* __restrict__ vg_wq, const float* __restrict__ vg_wk,
    float* __restrict__ h_m, float* __restrict__ pos_m,
    float* __restrict__ qbuf, float* __restrict__ kbuf)
{
    int mi = blockIdx.x;
    int lane = threadIdx.x;
    int node = midx[mi];
    h_m[mi*64 + lane] = h_local[node*64 + lane];
    if (lane < 3) pos_m[mi*3 + lane] = pos[node*3 + lane];
    if (lane < 32) {
        int j = lane & 15;
        const float* wm = (lane < 16) ? vg_wq : vg_wk;
        float acc = 0.0f;
        #pragma unroll
        for (int i = 0; i < 16; i++) acc += h_local[node*64 + i] * wm[i*16 + j];
        if (lane < 16) qbuf[mi*16 + j] = acc; else kbuf[mi*16 + j] = acc;
    }
}

// ---------------- map edges to master ids, build exist matrix ----------------
__global__ void k_exist(const int* __restrict__ src, const int* __restrict__ dst,
    const int* __restrict__ node2m, int* __restrict__ src_all, int* __restrict__ dst_all,
    float* __restrict__ mask_all, unsigned char* __restrict__ exist)
{
    int e = blockIdx.x * 256 + threadIdx.x;
    if (e >= E_) return;
    int sm = node2m[src[e]], dm = node2m[dst[e]];
    bool em = (sm >= 0) && (dm >= 0);
    int smc = sm >= 0 ? sm : 0;
    int dmc = dm >= 0 ? dm : 0;
    src_all[e] = smc; dst_all[e] = dmc; mask_all[e] = em ? 1.0f : 0.0f;
    if (em) exist[smc * K_ + dmc] = 1;
}

// ---------------- attention tiles: A_virtual output + candidate compaction ----------------
__global__ __launch_bounds__(256) void k_attn(const float* __restrict__ qbuf,
    const float* __restrict__ kbuf, const unsigned char* __restrict__ exist,
    float* __restrict__ Av, unsigned long long* __restrict__ cand, RState* st)
{
    constexpr int TB = K_ / 16;   // 125
    int bi = blockIdx.x / TB, bj = blockIdx.x % TB;
    int i0 = bi * 16, j0 = bj * 16;
    __shared__ float sq[16][17], sk[16][17];
    __shared__ int wb[4];
    __shared__ int bb;
    int tid = threadIdx.x;
    int r = tid >> 4, c = tid & 15;
    sq[r][c] = qbuf[(i0 + r) * 16 + c];
    sk[r][c] = kbuf[(j0 + r) * 16 + c];
    __syncthreads();
    int ti = tid >> 4, tj = tid & 15;
    float dot = 0.0f;
    #pragma unroll
    for (int cc = 0; cc < 16; cc++) dot += sq[ti][cc] * sk[tj][cc];
    float attn = 1.0f / (1.0f + expf(-dot * 0.25f));
    int gi = i0 + ti, gj = j0 + tj;
    int flat = gi * K_ + gj;
    bool ex = (exist[flat] != 0) || (gi == gj);
    bool av = (!ex) && (attn > 0.5f);
    Av[flat] = av ? 1.0f : 0.0f;

    unsigned long long keyv = ((unsigned long long)__float_as_uint(attn) << 32)
                            | (unsigned long long)(0xFFFFFFFFu - (unsigned)flat);
    int wid = tid >> 6, lane = tid & 63;
    unsigned long long b = __ballot(av);
    int wc = __popcll(b);
    if (lane == 0) wb[wid] = wc;
    __syncthreads();
    if (tid == 0) {
        int t = 0;
        for (int w = 0; w < 4; w++) { int cc2 = wb[w]; wb[w] = t; t += cc2; }
        bb = t ? (int)atomicAdd(&st->cand_count, (unsigned)t) : 0;
    }
    __syncthreads();
    if (av) {
        int slot = bb + wb[wid] + __popcll(b & ((1ull << lane) - 1ull));
        cand[slot] = keyv;
    }
}

// ---------------- radix select over 64-bit keys (8 x 8-bit MSB passes) ----------------
__global__ void k_radix_init(RState* st)
{
    unsigned int cc = st->cand_count;
    st->R = (cc < (unsigned)EV_) ? (int)cc : EV_;
    st->prefix = 0ull;
    st->sel_count = 0;
}

__global__ void k_hist(RState* st, const unsigned long long* __restrict__ cand, int p)
{
    __shared__ int lh[256];
    lh[threadIdx.x] = 0;
    __syncthreads();
    int n = (int)st->cand_count;
    unsigned long long pref = st->prefix;
    int sh_hi = 64 - 8 * p;
    int sh_d = 56 - 8 * p;
    int stride = gridDim.x * 256;
    for (int start = blockIdx.x * 256; start < n; start += stride) {
        int idx = start + threadIdx.x;
        if (idx < n) {
            unsigned long long kv = cand[idx];
            bool ok = (p == 0) ? true : ((kv >> sh_hi) == (pref >> sh_hi));
            if (ok) atomicAdd(&lh[(int)((kv >> sh_d) & 255ull)], 1);
        }
    }
    __syncthreads();
    int v = lh[threadIdx.x];
    if (v) atomicAdd(&st->hist[threadIdx.x], (unsigned)v);
}

__global__ void k_select(RState* st, int p)
{
    int R = st->R;
    if (R <= 0) {
        st->prefix = ~0ull;
        for (int i = 0; i < 256; i++) st->hist[i] = 0;
        return;
    }
    unsigned long long pref = st->prefix;
    int sh_d = 56 - 8 * p;
    int cum = 0;
    for (int d = 255; d >= 0; d--) {
        int hc = (int)st->hist[d];
        if (cum + hc >= R) {
            st->prefix = pref | ((unsigned long long)d << sh_d);
            st->R = R - cum;
            break;
        }
        cum += hc;
    }
    for (int i = 0; i < 256; i++) st->hist[i] = 0;
}

__global__ void k_vsel(RState* st, const unsigned long long* __restrict__ cand,
                       int* __restrict__ src_all, int* __restrict__ dst_all,
                       float* __restrict__ mask_all)
{
    int n = (int)st->cand_count;
    unsigned long long T = st->prefix;
    int lane = threadIdx.x & 63;
    int stride = gridDim.x * 256;
    for (int start = blockIdx.x * 256; start < n; start += stride) {
        int idx = start + threadIdx.x;
        bool sel = (idx < n) && (cand[idx] >= T);
        unsigned long long b = __ballot(sel);
        int wc = __popcll(b);
        int basep = 0;
        if (lane == 0 && wc) basep = (int)atomicAdd(&st->sel_count, (unsigned)wc);
        basep = __shfl(basep, 0);
        if (sel) {
            int slot = basep + __popcll(b & ((1ull << lane) - 1ull));
            if (slot < EV_) {
                unsigned flat = 0xFFFFFFFFu - (unsigned)(cand[idx] & 0xFFFFFFFFull);
                src_all[E_ + slot] = (int)(flat / (unsigned)K_);
                dst_all[E_ + slot] = (int)(flat % (unsigned)K_);
                mask_all[E_ + slot] = 1.0f;
            }
        }
    }
}

// ---------------- final mixing ----------------
__global__ void k_final(const float* __restrict__ h_local, const int* __restrict__ node2m,
    const float* __restrict__ aggm, const float* __restrict__ degm, const float* __restrict__ h_m,
    const float* __restrict__ m_out, float* __restrict__ out_h)
{
    int idx = blockIdx.x * 256 + threadIdx.x;
    if (idx >= N_ * C_) return;
    int i = idx >> 6, c = idx & 63;
    float mval = m_out[i];
    int mi = node2m[i];
    float hh = 0.0f;
    if (mi >= 0) hh = aggm[mi*64 + c] / fmaxf(degm[mi], 1.0f) + h_m[mi*64 + c];
    out_h[idx] = (1.0f - mval) * h_local[idx] + mval * hh;
}

__global__ void k_pos(const float* __restrict__ pos, float* __restrict__ out_pos)
{
    int idx = blockIdx.x * 256 + threadIdx.x;
    if (idx < N_ * 3) out_pos[idx] = pos[idx];
}

// ---------------- launch ----------------
extern "C" void kernel_launch(void* const* d_in, const int* in_sizes, int n_in,
                              void* d_out, int out_size, void* d_ws, size_t ws_size,
                              hipStream_t stream)
{
    (void)in_sizes; (void)n_in; (void)out_size; (void)ws_size;
    const float* h     = (const float*)d_in[0];
    const float* pos   = (const float*)d_in[1];
    const int*   eidx  = (const int*)d_in[2];
    const float* fc_w1 = (const float*)d_in[3];
    const float* fc_b1 = (const float*)d_in[4];
    const float* fc_w2 = (const float*)d_in[5];
    const float* fc_b2 = (const float*)d_in[6];
    const float* lin_w = (const float*)d_in[7];
    const float* ms_w1 = (const float*)d_in[8];
    const float* ms_b1 = (const float*)d_in[9];
    const float* ms_w2 = (const float*)d_in[10];
    const float* ms_b2 = (const float*)d_in[11];
    const float* vg_wq = (const float*)d_in[12];
    const float* vg_wk = (const float*)d_in[13];

    char* ws = (char*)d_ws;
    float* h_local = (float*)(ws + OFF_HLOCAL);
    float* agg     = (float*)(ws + OFF_AGG);
    float* deg     = (float*)(ws + OFF_DEG);
    unsigned long long* key = (unsigned long long*)(ws + OFF_KEY);
    float* score   = (float*)(ws + OFF_SCORE);
    int*   selflag = (int*)(ws + OFF_SELF);
    int*   node2m  = (int*)(ws + OFF_N2M);
    int*   midx    = (int*)(ws + OFF_MIDX);
    float* h_m     = (float*)(ws + OFF_HM);
    float* pos_m   = (float*)(ws + OFF_POSM);
    float* qbuf    = (float*)(ws + OFF_Q);
    float* kbuf    = (float*)(ws + OFF_KBUF);
    unsigned char* exist = (unsigned char*)(ws + OFF_EXIST);
    int*   src_all = (int*)(ws + OFF_SRCA);
    int*   dst_all = (int*)(ws + OFF_DSTA);
    float* mask_all = (float*)(ws + OFF_MASKA);
    float* aggm    = (float*)(ws + OFF_AGGM);
    float* degm    = (float*)(ws + OFF_DEGM);
    float* w0      = (float*)(ws + OFF_W0);
    int*   w0nz    = (int*)(ws + OFF_W0NZ);
    RState* st     = (RState*)(ws + OFF_STATE);
    unsigned long long* cand = (unsigned long long*)(ws + OFF_CAND);

    float* out_h   = (float*)d_out;
    float* out_pos = out_h + (size_t)N_ * C_;
    float* out_av  = out_pos + (size_t)N_ * 3;
    float* out_m   = out_av + (size_t)K_ * K_;

    // zero-init (d_ws is poisoned with 0xAA before every call)
    hipMemsetAsync(ws + OFF_AGG, 0, 5200000, stream);                 // agg + deg
    hipMemsetAsync(ws + OFF_EXIST, 0, 4000000, stream);               // exist
    hipMemsetAsync(ws + OFF_AGGM, 0, 520000, stream);                 // aggm + degm
    hipMemsetAsync(ws + OFF_STATE, 0, sizeof(RState), stream);        // radix state
    hipMemsetAsync(ws + OFF_SRCA + (size_t)E_*4, 0, (size_t)EV_*4, stream);
    hipMemsetAsync(ws + OFF_DSTA + (size_t)E_*4, 0, (size_t)EV_*4, stream);
    hipMemsetAsync(ws + OFF_MASKA + (size_t)E_*4, 0, (size_t)EV_*4, stream);

    k_w0<<<1, 576, 0, stream>>>(fc_b1, fc_w2, fc_b2, w0, w0nz);

    k_conv<<<(E_ + 3) / 4, 256, 0, stream>>>(E_, eidx, eidx + E_, nullptr, h, pos,
        fc_w1, fc_b1, fc_w2, fc_b2, lin_w, w0, w0nz, agg, deg);

    k_hlocal<<<(N_ * C_ + 255) / 256, 256, 0, stream>>>(h, agg, deg, h_local);

    k_score<<<(N_ + 3) / 4, 256, 0, stream>>>(h_local, ms_w1, ms_b1, ms_w2, ms_b2, score, key);

    k_rank<<<(N_ + 255) / 256, 256, 0, stream>>>(key, score, selflag, out_m);

    k_scan<<<1, 1024, 0, stream>>>(selflag, node2m, midx);

    k_master<<<K_, 64, 0, stream>>>(midx, h_local, pos, vg_wq, vg_wk, h_m, pos_m, qbuf, kbuf);

    k_exist<<<(E_ + 255) / 256, 256, 0, stream>>>(eidx, eidx + E_, node2m,
        src_all, dst_all, mask_all, exist);

    k_attn<<<(K_ / 16) * (K_ / 16), 256, 0, stream>>>(qbuf, kbuf, exist, out_av, cand, st);

    k_radix_init<<<1, 1, 0, stream>>>(st);
    for (int p = 0; p < 8; p++) {
        k_hist<<<512, 256, 0, stream>>>(st, cand, p);
        k_select<<<1, 1, 0, stream>>>(st, p);
    }
    k_vsel<<<512, 256, 0, stream>>>(st, cand, src_all, dst_all, mask_all);

    k_conv<<<(EALL_ + 3) / 4, 256, 0, stream>>>(EALL_, src_all, dst_all, mask_all, h_m, pos_m,
        fc_w1, fc_b1, fc_w2, fc_b2, lin_w, w0, w0nz, aggm, degm);

    k_final<<<(N_ * C_ + 255) / 256, 256, 0, stream>>>(h_local, node2m, aggm, degm, h_m, out_m, out_h);

    k_pos<<<(N_ * 3 + 255) / 256, 256, 0, stream>>>(pos, out_pos);
}

// Round 2
// 1061.052 us; speedup vs baseline: 1.4930x; 1.4930x over previous
//
#include <hip/hip_runtime.h>
#include <stdint.h>

// ---------------- problem constants ----------------
constexpr int N_   = 20000;
constexpr int E_   = 160000;
constexpr int C_   = 64;
constexpr int K_   = 2000;
constexpr int EV_  = 32000;
constexpr int EALL_ = E_ + EV_;          // 192000
constexpr int CSH_ = 576;                // C*SH
constexpr int TB_  = 32;                 // edges per block in batched conv

// ---------------- workspace layout (bytes) ----------------
constexpr size_t OFF_HLOCAL = 0;                  // N*C f32
constexpr size_t OFF_AGG    = 5120000;            // N*C f32
constexpr size_t OFF_DEG    = 10240000;           // N f32
constexpr size_t OFF_KEY    = 10320000;           // N u64
constexpr size_t OFF_SCORE  = 10480000;           // N f32
constexpr size_t OFF_SELF   = 10560000;           // N i32
constexpr size_t OFF_N2M    = 10640000;           // N i32
constexpr size_t OFF_MIDX   = 10720000;           // K i32
constexpr size_t OFF_HM     = 10728000;           // K*C f32
constexpr size_t OFF_POSM   = 11240000;           // K*3 f32
constexpr size_t OFF_Q      = 11264000;           // K*16 f32
constexpr size_t OFF_KBUF   = 11392000;           // K*16 f32
constexpr size_t OFF_EXIST  = 11520000;           // K*K u8
constexpr size_t OFF_SRCA   = 15520000;           // EALL i32
constexpr size_t OFF_DSTA   = 16288000;           // EALL i32
constexpr size_t OFF_MASKA  = 17056000;           // EALL f32
constexpr size_t OFF_AGGM   = 17824000;           // K*C f32
constexpr size_t OFF_DEGM   = 18336000;           // K f32
constexpr size_t OFF_W0     = 18344000;           // 576 f32
constexpr size_t OFF_W0NZ   = 18346304;           // i32
constexpr size_t OFF_STATE  = 18346400;           // RState + 2 edge counters
constexpr size_t OFF_CAND   = 18348000;           // K*K u64 (32 MB); EDATA overlays this (stream-ordered safe)
constexpr size_t OFF_RANK   = 50348000;           // N i32 rank counts
// total ~50.43 MB

struct RState {
    unsigned long long prefix;
    int R;
    unsigned int cand_count;
    unsigned int sel_count;
    unsigned int pad;
    unsigned int hist[256];
};

// ---------------- w0nz: does the edge-independent weight (env==0 path) vanish? ----------------
__global__ void k_w0(const float* __restrict__ fc_b1, const float* __restrict__ fc_w2,
                     const float* __restrict__ fc_b2, float* __restrict__ w0, int* __restrict__ w0nz)
{
    __shared__ float hid0[64];
    __shared__ int nz;
    int tid = threadIdx.x;
    if (tid == 0) nz = 0;
    if (tid < 64) hid0[tid] = fmaxf(fc_b1[tid], 0.0f);
    __syncthreads();
    if (tid < CSH_) {
        float acc = fc_b2[tid];
        for (int k = 0; k < 64; k++) acc += hid0[k] * fc_w2[k * CSH_ + tid];
        w0[tid] = acc;
        if (acc != 0.0f) atomicOr(&nz, 1);
    }
    __syncthreads();
    if (tid == 0) *w0nz = nz;
}

// ---------------- edge prep: geometry + bessel, deg atomics, compact contributing edges ----------------
// edata layout per edge (20 f32): ef[8], sh[9], src(bits), dst(bits), msk
__global__ __launch_bounds__(256) void k_prep(
    int n_edges, const int* __restrict__ src, const int* __restrict__ dst,
    const float* __restrict__ mask, const float* __restrict__ posn,
    const int* __restrict__ w0nz, float* __restrict__ deg,
    float* __restrict__ edata, unsigned int* __restrict__ cnt)
{
    int e = blockIdx.x * 256 + threadIdx.x;
    bool valid = e < n_edges;
    int s_i = 0, d_i = 0; float msk = 0.0f;
    if (valid) {
        s_i = src[e]; d_i = dst[e];
        msk = mask ? mask[e] : 1.0f;
    }
    bool active = valid && (msk != 0.0f);

    float vx = 0.f, vy = 0.f, vz = 0.f;
    if (active) {
        vx = posn[s_i*3+0] - posn[d_i*3+0];
        vy = posn[s_i*3+1] - posn[d_i*3+1];
        vz = posn[s_i*3+2] - posn[d_i*3+2];
    }
    float r = sqrtf(vx*vx + vy*vy + vz*vz + 1e-12f);
    float invr = 1.0f / r;
    float x = vx*invr, y = vy*invr, z = vz*invr;
    const float s3 = 1.7320508075688772f, s15 = 3.872983346207417f, s5 = 2.23606797749979f;
    float sh[9];
    sh[0] = 1.0f; sh[1] = s3*x; sh[2] = s3*y; sh[3] = s3*z;
    sh[4] = s15*x*y; sh[5] = s15*y*z; sh[6] = 0.5f*s5*(3.0f*z*z - 1.0f);
    sh[7] = s15*x*z; sh[8] = 0.5f*s15*(x*x - y*y);

    float u = r * 0.2f; u = u > 1.0f ? 1.0f : u;
    float u2 = u*u, u6 = u2*u2*u2, u7 = u6*u, u8 = u7*u;
    float env = 1.0f - 28.0f*u6 + 48.0f*u7 - 21.0f*u8;
    float rc = r > 1e-9f ? r : 1e-9f;
    const float bpref = 0.6324555320336759f;      // sqrt(2/5)
    const float PIov5 = 0.6283185307179586f;
    float ef[8];
    #pragma unroll
    for (int n = 0; n < 8; n++)
        ef[n] = bpref * sinf(PIov5 * r * (float)(n + 1)) / rc * env;

    if (active) atomicAdd(&deg[s_i], msk);

    bool contrib = active && !((env == 0.0f) && (*w0nz == 0));
    int lane = threadIdx.x & 63;
    unsigned long long b = __ballot(contrib);
    int wc = __popcll(b);
    int base = 0;
    if (lane == 0 && wc) base = (int)atomicAdd(cnt, (unsigned)wc);
    base = __shfl(base, 0);
    if (contrib) {
        int slot = base + __popcll(b & ((1ull << lane) - 1ull));
        float* p = edata + (size_t)slot * 20;
        #pragma unroll
        for (int n = 0; n < 8; n++) p[n] = ef[n];
        #pragma unroll
        for (int t = 0; t < 9; t++) p[8+t] = sh[t];
        p[17] = __int_as_float(s_i);
        p[18] = __int_as_float(d_i);
        p[19] = msk;
    }
}

// ---------------- batched conv GEMM: 32 edges/block, LDS-tiled weights ----------------
__global__ __launch_bounds__(256, 2) void k_convg(
    const unsigned int* __restrict__ cnt, const float* __restrict__ edata,
    const float* __restrict__ hn,
    const float* __restrict__ fc_w1, const float* __restrict__ fc_b1,
    const float* __restrict__ fc_w2, const float* __restrict__ fc_b2,
    const float* __restrict__ lin_w, float* __restrict__ agg)
{
    __shared__ float s_misc[TB_ * 12];                 // sh[9], src, msk, pad
    __shared__ float s_hid[TB_ * 68];                  // padded rows (bank spread)
    __shared__ float s_hd[TB_ * 64];
    __shared__ float s_tp[TB_ * 68];
    __shared__ __align__(16) float s_w2[4096];         // [k][jj] chunk of fc_w2
    __shared__ __align__(16) float s_lw[4096];         // [jj][o] chunk of lin_w

    const int tid = threadIdx.x;
    const int jj4 = (tid & 15) * 4;
    const int eg  = tid >> 4;                          // 0..15
    const int e0 = eg, e1 = eg + 16;

    const int nheavy = (int)*cnt;
    const int nblk = (nheavy + TB_ - 1) / TB_;

    for (int blk = blockIdx.x; blk < nblk; blk += gridDim.x) {
        const int ebase = blk * TB_;
        int nE = nheavy - ebase; if (nE > TB_) nE = TB_;

        // stage misc (sh, src, msk)
        for (int idx = tid; idx < TB_ * 12; idx += 256) {
            int e = idx / 12, f = idx - 12 * e;
            float v = 0.0f;
            if (e < nE) {
                const float* p = edata + (size_t)(ebase + e) * 20;
                v = (f < 9) ? p[8 + f] : (f == 9) ? p[17] : (f == 10) ? p[19] : 0.0f;
            }
            s_misc[idx] = v;
        }
        // hid = relu(ef @ W1 + b1); gather h[dst]
        for (int idx = tid; idx < TB_ * 64; idx += 256) {
            int e = idx >> 6, k = idx & 63;
            float hv = 0.0f, hdv = 0.0f;
            if (e < nE) {
                const float* p = edata + (size_t)(ebase + e) * 20;
                float acc = fc_b1[k];
                #pragma unroll
                for (int n = 0; n < 8; n++) acc += p[n] * fc_w1[n * 64 + k];
                hv = fmaxf(acc, 0.0f);
                int dsti = __float_as_int(p[18]);
                hdv = hn[dsti * 64 + k];
            }
            s_hid[e * 68 + k] = hv;
            s_hd[e * 64 + k] = hdv;
        }
        float m0[4] = {0.f,0.f,0.f,0.f}, m1[4] = {0.f,0.f,0.f,0.f};
        __syncthreads();

        for (int cj = 0; cj < 9; cj++) {
            const int j0 = cj * 64;
            // stage weight chunks
            for (int i4 = tid; i4 < 1024; i4 += 256) {
                int k = i4 >> 4, q4 = (i4 & 15) * 4;
                float4 v = *reinterpret_cast<const float4*>(&fc_w2[k * CSH_ + j0 + q4]);
                *reinterpret_cast<float4*>(&s_w2[k * 64 + q4]) = v;
            }
            for (int i4 = tid; i4 < 1024; i4 += 256) {
                float4 v = *reinterpret_cast<const float4*>(&lin_w[j0 * 64 + i4 * 4]);
                *reinterpret_cast<float4*>(&s_lw[i4 * 4]) = v;
            }
            __syncthreads();

            // GEMM1: w[e][j] = b2[j] + hid[e][:] @ W2[:, j]
            float a0[4], a1[4];
            #pragma unroll
            for (int q = 0; q < 4; q++) { float b = fc_b2[j0 + jj4 + q]; a0[q] = b; a1[q] = b; }
            for (int k = 0; k < 64; k++) {
                float4 w4 = *reinterpret_cast<const float4*>(&s_w2[k * 64 + jj4]);
                float h0 = s_hid[e0 * 68 + k], h1 = s_hid[e1 * 68 + k];
                a0[0] += h0 * w4.x; a0[1] += h0 * w4.y; a0[2] += h0 * w4.z; a0[3] += h0 * w4.w;
                a1[0] += h1 * w4.x; a1[1] += h1 * w4.y; a1[2] += h1 * w4.z; a1[3] += h1 * w4.w;
            }
            // tp = h_dst[c] * sh[si] * w
            #pragma unroll
            for (int q = 0; q < 4; q++) {
                int j = j0 + jj4 + q; int c = j / 9; int si = j - 9 * c;
                s_tp[e0 * 68 + jj4 + q] = s_hd[e0 * 64 + c] * s_misc[e0 * 12 + si] * a0[q];
                s_tp[e1 * 68 + jj4 + q] = s_hd[e1 * 64 + c] * s_misc[e1 * 12 + si] * a1[q];
            }
            __syncthreads();

            // GEMM2: msg[e][o] += tp[e][:] @ lin_w_chunk[:, o]
            for (int jj = 0; jj < 64; jj++) {
                float4 l4 = *reinterpret_cast<const float4*>(&s_lw[jj * 64 + jj4]);
                float t0 = s_tp[e0 * 68 + jj], t1 = s_tp[e1 * 68 + jj];
                m0[0] += t0 * l4.x; m0[1] += t0 * l4.y; m0[2] += t0 * l4.z; m0[3] += t0 * l4.w;
                m1[0] += t1 * l4.x; m1[1] += t1 * l4.y; m1[2] += t1 * l4.z; m1[3] += t1 * l4.w;
            }
            __syncthreads();
        }

        float mk0 = s_misc[e0 * 12 + 10], mk1 = s_misc[e1 * 12 + 10];
        if (mk0 != 0.0f) {
            int s0 = __float_as_int(s_misc[e0 * 12 + 9]);
            #pragma unroll
            for (int q = 0; q < 4; q++) atomicAdd(&agg[s0 * 64 + jj4 + q], m0[q] * mk0);
        }
        if (mk1 != 0.0f) {
            int s1 = __float_as_int(s_misc[e1 * 12 + 9]);
            #pragma unroll
            for (int q = 0; q < 4; q++) atomicAdd(&agg[s1 * 64 + jj4 + q], m1[q] * mk1);
        }
        __syncthreads();
    }
}

// ---------------- h_local = h + agg/max(deg,1) ----------------
__global__ void k_hlocal(const float* __restrict__ h, const float* __restrict__ agg,
                         const float* __restrict__ deg, float* __restrict__ h_local)
{
    int idx = blockIdx.x * 256 + threadIdx.x;
    if (idx < N_ * C_) {
        float d = deg[idx >> 6];
        h_local[idx] = h[idx] + agg[idx] / fmaxf(d, 1.0f);
    }
}

// ---------------- per-node score + composite sort key ----------------
__global__ __launch_bounds__(256) void k_score(const float* __restrict__ h_local,
    const float* __restrict__ ms_w1, const float* __restrict__ ms_b1,
    const float* __restrict__ ms_w2, const float* __restrict__ ms_b2,
    float* __restrict__ score, unsigned long long* __restrict__ key)
{
    int wid = threadIdx.x >> 6, lane = threadIdx.x & 63;
    int n = blockIdx.x * 4 + wid;
    if (n >= N_) return;
    float acc = ms_b1[lane];
    #pragma unroll
    for (int i = 0; i < 16; i++) acc += h_local[n*64 + i] * ms_w1[i*64 + lane];
    acc = fmaxf(acc, 0.0f);
    float part = acc * ms_w2[lane];
    #pragma unroll
    for (int off = 32; off > 0; off >>= 1) part += __shfl_xor(part, off);
    if (lane == 0) {
        float s = part + ms_b2[0];
        float sc = 1.0f / (1.0f + expf(-s));
        score[n] = sc;
        key[n] = ((unsigned long long)__float_as_uint(sc) << 32)
               | (unsigned long long)(0xFFFFFFFFu - (unsigned)n);
    }
}

// ---------------- exact top-K rank counting, split over 8 j-segments ----------------
__global__ void k_rank(const unsigned long long* __restrict__ key, int* __restrict__ rankcnt)
{
    __shared__ unsigned long long tile[256];
    int i = blockIdx.x * 256 + threadIdx.x;
    int seg = blockIdx.y;
    int lo = seg * 2500, hi = lo + 2500;
    if (hi > N_) hi = N_;
    unsigned long long my = (i < N_) ? key[i] : ~0ull;
    int cnt = 0;
    for (int t0 = lo; t0 < hi; t0 += 256) {
        int idx = t0 + threadIdx.x;
        tile[threadIdx.x] = (idx < hi) ? key[idx] : 0ull;
        __syncthreads();
        int lim = hi - t0; if (lim > 256) lim = 256;
        for (int j = 0; j < lim; j++) cnt += (tile[j] > my) ? 1 : 0;
        __syncthreads();
    }
    if (i < N_ && cnt) atomicAdd(&rankcnt[i], cnt);
}

__global__ void k_rank_fin(const int* __restrict__ rankcnt, const float* __restrict__ score,
                           int* __restrict__ selflag, float* __restrict__ m_out)
{
    int i = blockIdx.x * 256 + threadIdx.x;
    if (i >= N_) return;
    int sel = (rankcnt[i] < K_) ? 1 : 0;
    selflag[i] = sel;
    m_out[i] = sel ? score[i] : 0.0f;
}

// ---------------- single-block prefix scan: node2m + master_idx ----------------
__global__ void k_scan(const int* __restrict__ selflag, int* __restrict__ node2m,
                       int* __restrict__ midx)
{
    __shared__ int ssum[1024];
    int tid = threadIdx.x;
    int start = tid * 20;
    int c = 0;
    for (int k = 0; k < 20; k++) { int idx = start + k; if (idx < N_) c += selflag[idx]; }
    ssum[tid] = c;
    __syncthreads();
    for (int off = 1; off < 1024; off <<= 1) {
        int v = (tid >= off) ? ssum[tid - off] : 0;
        __syncthreads();
        ssum[tid] += v;
        __syncthreads();
    }
    int run = ssum[tid] - c;
    for (int k = 0; k < 20; k++) {
        int idx = start + k;
        if (idx < N_) {
            if (selflag[idx]) { node2m[idx] = run; midx[run] = idx; run++; }
            else node2m[idx] = -1;
        }
    }
}

// ---------------- gather master nodes + q/k projections ----------------
__global__ void k_master(const int* __restrict__ midx, const float* __restrict__ h_local,
    const float* __restrict__ pos, const float* __restrict__ vg_wq, const float* __restrict__ vg_wk,
    float* __restrict__ h_m, float* __restrict__ pos_m,
    float* __restrict__ qbuf, float* __restrict__ kbuf)
{
    int mi = blockIdx.x;
    int lane = threadIdx.x;
    int node = midx[mi];
    h_m[mi*64 + lane] = h_local[node*64 + lane];
    if (lane < 3) pos_m[mi*3 + lane] = pos[node*3 + lane];
    if (lane < 32) {
        int j = lane & 15;
        const float* wm = (lane < 16) ? vg_wq : vg_wk;
        float acc = 0.0f;
        #pragma unroll
        for (int i = 0; i < 16; i++) acc += h_local[node*64 + i] * wm[i*16 + j];
        if (lane < 16) qbuf[mi*16 + j] = acc; else kbuf[mi*16 + j] = acc;
    }
}

// ---------------- map edges to master ids, build exist matrix ----------------
__global__ void k_exist(const int* __restrict__ src, const int* __restrict__ dst,
    const int* __restrict__ node2m, int* __restrict__ src_all, int* __restrict__ dst_all,
    float* __restrict__ mask_all, unsigned char* __restrict__ exist)
{
    int e = blockIdx.x * 256 + threadIdx.x;
    if (e >= E_) return;
    int sm = node2m[src[e]], dm = node2m[dst[e]];
    bool em = (sm >= 0) && (dm >= 0);
    int smc = sm >= 0 ? sm : 0;
    int dmc = dm >= 0 ? dm : 0;
    src_all[e] = smc; dst_all[e] = dmc; mask_all[e] = em ? 1.0f : 0.0f;
    if (em) exist[smc * K_ + dmc] = 1;
}

// ---------------- attention tiles: A_virtual output + candidate compaction ----------------
__global__ __launch_bounds__(256) void k_attn(const float* __restrict__ qbuf,
    const float* __restrict__ kbuf, const unsigned char* __restrict__ exist,
    float* __restrict__ Av, unsigned long long* __restrict__ cand, RState* st)
{
    constexpr int TBK = K_ / 16;   // 125
    int bi = blockIdx.x / TBK, bj = blockIdx.x % TBK;
    int i0 = bi * 16, j0 = bj * 16;
    __shared__ float sq[16][17], sk[16][17];
    __shared__ int wb[4];
    __shared__ int bb;
    int tid = threadIdx.x;
    int r = tid >> 4, c = tid & 15;
    sq[r][c] = qbuf[(i0 + r) * 16 + c];
    sk[r][c] = kbuf[(j0 + r) * 16 + c];
    __syncthreads();
    int ti = tid >> 4, tj = tid & 15;
    float dot = 0.0f;
    #pragma unroll
    for (int cc = 0; cc < 16; cc++) dot += sq[ti][cc] * sk[tj][cc];
    float attn = 1.0f / (1.0f + expf(-dot * 0.25f));
    int gi = i0 + ti, gj = j0 + tj;
    int flat = gi * K_ + gj;
    bool ex = (exist[flat] != 0) || (gi == gj);
    bool av = (!ex) && (attn > 0.5f);
    Av[flat] = av ? 1.0f : 0.0f;

    unsigned long long keyv = ((unsigned long long)__float_as_uint(attn) << 32)
                            | (unsigned long long)(0xFFFFFFFFu - (unsigned)flat);
    int wid = tid >> 6, lane = tid & 63;
    unsigned long long b = __ballot(av);
    int wc = __popcll(b);
    if (lane == 0) wb[wid] = wc;
    __syncthreads();
    if (tid == 0) {
        int t = 0;
        for (int w = 0; w < 4; w++) { int cc2 = wb[w]; wb[w] = t; t += cc2; }
        bb = t ? (int)atomicAdd(&st->cand_count, (unsigned)t) : 0;
    }
    __syncthreads();
    if (av) {
        int slot = bb + wb[wid] + __popcll(b & ((1ull << lane) - 1ull));
        cand[slot] = keyv;
    }
}

// ---------------- radix select over 64-bit keys ----------------
__global__ void k_radix_init(RState* st)
{
    unsigned int cc = st->cand_count;
    st->R = (cc < (unsigned)EV_) ? (int)cc : EV_;
    st->prefix = 0ull;
    st->sel_count = 0;
}

__global__ void k_hist(RState* st, const unsigned long long* __restrict__ cand, int p)
{
    __shared__ int lh[256];
    lh[threadIdx.x] = 0;
    __syncthreads();
    int n = (int)st->cand_count;
    unsigned long long pref = st->prefix;
    int sh_hi = 64 - 8 * p;
    int sh_d = 56 - 8 * p;
    int stride = gridDim.x * 256;
    for (int start = blockIdx.x * 256; start < n; start += stride) {
        int idx = start + threadIdx.x;
        if (idx < n) {
            unsigned long long kv = cand[idx];
            bool ok = (p == 0) ? true : ((kv >> sh_hi) == (pref >> sh_hi));
            if (ok) atomicAdd(&lh[(int)((kv >> sh_d) & 255ull)], 1);
        }
    }
    __syncthreads();
    int v = lh[threadIdx.x];
    if (v) atomicAdd(&st->hist[threadIdx.x], (unsigned)v);
}

__global__ void k_select(RState* st, int p)
{
    int R = st->R;
    if (R <= 0) {
        st->prefix = ~0ull;
        for (int i = 0; i < 256; i++) st->hist[i] = 0;
        return;
    }
    unsigned long long pref = st->prefix;
    int sh_d = 56 - 8 * p;
    int cum = 0;
    for (int d = 255; d >= 0; d--) {
        int hc = (int)st->hist[d];
        if (cum + hc >= R) {
            st->prefix = pref | ((unsigned long long)d << sh_d);
            st->R = R - cum;
            break;
        }
        cum += hc;
    }
    for (int i = 0; i < 256; i++) st->hist[i] = 0;
}

__global__ void k_vsel(RState* st, const unsigned long long* __restrict__ cand,
                       int* __restrict__ src_all, int* __restrict__ dst_all,
                       float* __restrict__ mask_all)
{
    int n = (int)st->cand_count;
    unsigned long long T = st->prefix;
    int lane = threadIdx.x & 63;
    int stride = gridDim.x * 256;
    for (int start = blockIdx.x * 256; start < n; start += stride) {
        int idx = start + threadIdx.x;
        bool sel = (idx < n) && (cand[idx] >= T);
        unsigned long long b = __ballot(sel);
        int wc = __popcll(b);
        int basep = 0;
        if (lane == 0 && wc) basep = (int)atomicAdd(&st->sel_count, (unsigned)wc);
        basep = __shfl(basep, 0);
        if (sel) {
            int slot = basep + __popcll(b & ((1ull << lane) - 1ull));
            if (slot < EV_) {
                unsigned flat = 0xFFFFFFFFu - (unsigned)(cand[idx] & 0xFFFFFFFFull);
                src_all[E_ + slot] = (int)(flat / (unsigned)K_);
                dst_all[E_ + slot] = (int)(flat % (unsigned)K_);
                mask_all[E_ + slot] = 1.0f;
            }
        }
    }
}

// ---------------- final mixing ----------------
__global__ void k_final(const float* __restrict__ h_local, const int* __restrict__ node2m,
    const float* __restrict__ aggm, const float* __restrict__ degm, const float* __restrict__ h_m,
    const float* __restrict__ m_out, float* __restrict__ out_h)
{
    int idx = blockIdx.x * 256 + threadIdx.x;
    if (idx >= N_ * C_) return;
    int i = idx >> 6, c = idx & 63;
    float mval = m_out[i];
    int mi = node2m[i];
    float hh = 0.0f;
    if (mi >= 0) hh = aggm[mi*64 + c] / fmaxf(degm[mi], 1.0f) + h_m[mi*64 + c];
    out_h[idx] = (1.0f - mval) * h_local[idx] + mval * hh;
}

__global__ void k_pos(const float* __restrict__ pos, float* __restrict__ out_pos)
{
    int idx = blockIdx.x * 256 + threadIdx.x;
    if (idx < N_ * 3) out_pos[idx] = pos[idx];
}

// ---------------- launch ----------------
extern "C" void kernel_launch(void* const* d_in, const int* in_sizes, int n_in,
                              void* d_out, int out_size, void* d_ws, size_t ws_size,
                              hipStream_t stream)
{
    (void)in_sizes; (void)n_in; (void)out_size; (void)ws_size;
    const float* h     = (const float*)d_in[0];
    const float* pos   = (const float*)d_in[1];
    const int*   eidx  = (const int*)d_in[2];
    const float* fc_w1 = (const float*)d_in[3];
    const float* fc_b1 = (const float*)d_in[4];
    const float* fc_w2 = (const float*)d_in[5];
    const float* fc_b2 = (const float*)d_in[6];
    const float* lin_w = (const float*)d_in[7];
    const float* ms_w1 = (const float*)d_in[8];
    const float* ms_b1 = (const float*)d_in[9];
    const float* ms_w2 = (const float*)d_in[10];
    const float* ms_b2 = (const float*)d_in[11];
    const float* vg_wq = (const float*)d_in[12];
    const float* vg_wk = (const float*)d_in[13];

    char* ws = (char*)d_ws;
    float* h_local = (float*)(ws + OFF_HLOCAL);
    float* agg     = (float*)(ws + OFF_AGG);
    float* deg     = (float*)(ws + OFF_DEG);
    unsigned long long* key = (unsigned long long*)(ws + OFF_KEY);
    float* score   = (float*)(ws + OFF_SCORE);
    int*   selflag = (int*)(ws + OFF_SELF);
    int*   node2m  = (int*)(ws + OFF_N2M);
    int*   midx    = (int*)(ws + OFF_MIDX);
    float* h_m     = (float*)(ws + OFF_HM);
    float* pos_m   = (float*)(ws + OFF_POSM);
    float* qbuf    = (float*)(ws + OFF_Q);
    float* kbuf    = (float*)(ws + OFF_KBUF);
    unsigned char* exist = (unsigned char*)(ws + OFF_EXIST);
    int*   src_all = (int*)(ws + OFF_SRCA);
    int*   dst_all = (int*)(ws + OFF_DSTA);
    float* mask_all = (float*)(ws + OFF_MASKA);
    float* aggm    = (float*)(ws + OFF_AGGM);
    float* degm    = (float*)(ws + OFF_DEGM);
    float* w0      = (float*)(ws + OFF_W0);
    int*   w0nz    = (int*)(ws + OFF_W0NZ);
    RState* st     = (RState*)(ws + OFF_STATE);
    unsigned int* cnt0 = (unsigned int*)(ws + OFF_STATE + sizeof(RState));
    unsigned int* cnt1 = cnt0 + 1;
    unsigned long long* cand = (unsigned long long*)(ws + OFF_CAND);
    float* edata   = (float*)(ws + OFF_CAND);        // overlays cand (stream-ordered: safe)
    int*   rankcnt = (int*)(ws + OFF_RANK);

    float* out_h   = (float*)d_out;
    float* out_pos = out_h + (size_t)N_ * C_;
    float* out_av  = out_pos + (size_t)N_ * 3;
    float* out_m   = out_av + (size_t)K_ * K_;

    // zero-init (d_ws is poisoned with 0xAA before every call)
    hipMemsetAsync(ws + OFF_AGG, 0, 5200000, stream);                 // agg + deg
    hipMemsetAsync(ws + OFF_EXIST, 0, 4000000, stream);               // exist
    hipMemsetAsync(ws + OFF_AGGM, 0, 520000, stream);                 // aggm + degm
    hipMemsetAsync(ws + OFF_STATE, 0, sizeof(RState) + 8, stream);    // radix state + edge counters
    hipMemsetAsync(ws + OFF_RANK, 0, (size_t)N_ * 4, stream);         // rank counts
    hipMemsetAsync(ws + OFF_SRCA + (size_t)E_*4, 0, (size_t)EV_*4, stream);
    hipMemsetAsync(ws + OFF_DSTA + (size_t)E_*4, 0, (size_t)EV_*4, stream);
    hipMemsetAsync(ws + OFF_MASKA + (size_t)E_*4, 0, (size_t)EV_*4, stream);

    k_w0<<<1, 576, 0, stream>>>(fc_b1, fc_w2, fc_b2, w0, w0nz);

    // ---- conv 1 on full graph ----
    k_prep<<<E_ / 256, 256, 0, stream>>>(E_, eidx, eidx + E_, nullptr, pos, w0nz, deg, edata, cnt0);
    k_convg<<<2048, 256, 0, stream>>>(cnt0, edata, h, fc_w1, fc_b1, fc_w2, fc_b2, lin_w, agg);

    k_hlocal<<<(N_ * C_ + 255) / 256, 256, 0, stream>>>(h, agg, deg, h_local);

    k_score<<<(N_ + 3) / 4, 256, 0, stream>>>(h_local, ms_w1, ms_b1, ms_w2, ms_b2, score, key);

    k_rank<<<dim3((N_ + 255) / 256, 8), 256, 0, stream>>>(key, rankcnt);
    k_rank_fin<<<(N_ + 255) / 256, 256, 0, stream>>>(rankcnt, score, selflag, out_m);

    k_scan<<<1, 1024, 0, stream>>>(selflag, node2m, midx);

    k_master<<<K_, 64, 0, stream>>>(midx, h_local, pos, vg_wq, vg_wk, h_m, pos_m, qbuf, kbuf);

    k_exist<<<(E_ + 255) / 256, 256, 0, stream>>>(eidx, eidx + E_, node2m,
        src_all, dst_all, mask_all, exist);

    k_attn<<<(K_ / 16) * (K_ / 16), 256, 0, stream>>>(qbuf, kbuf, exist, out_av, cand, st);

    k_radix_init<<<1, 1, 0, stream>>>(st);
    for (int p = 0; p < 8; p++) {
        k_hist<<<512, 256, 0, stream>>>(st, cand, p);
        k_select<<<1, 1, 0, stream>>>(st, p);
    }
    k_vsel<<<512, 256, 0, stream>>>(st, cand, src_all, dst_all, mask_all);

    // ---- conv 2 on master graph (real + virtual edges) ----
    k_prep<<<EALL_ / 256, 256, 0, stream>>>(EALL_, src_all, dst_all, mask_all, pos_m, w0nz,
                                            degm, edata, cnt1);
    k_convg<<<2048, 256, 0, stream>>>(cnt1, edata, h_m, fc_w1, fc_b1, fc_w2, fc_b2, lin_w, aggm);

    k_final<<<(N_ * C_ + 255) / 256, 256, 0, stream>>>(h_local, node2m, aggm, degm, h_m, out_m, out_h);

    k_pos<<<(N_ * 3 + 255) / 256, 256, 0, stream>>>(pos, out_pos);
}

// Round 3
// 922.695 us; speedup vs baseline: 1.7169x; 1.1499x over previous
//
#include <hip/hip_runtime.h>
#include <stdint.h>

// ---------------- problem constants ----------------
constexpr int N_   = 20000;
constexpr int E_   = 160000;
constexpr int C_   = 64;
constexpr int K_   = 2000;
constexpr int EV_  = 32000;
constexpr int EALL_ = E_ + EV_;          // 192000
constexpr int CSH_ = 576;                // C*SH
constexpr int TB_  = 32;                 // edges per block in batched conv

// ---------------- workspace layout (bytes) ----------------
constexpr size_t OFF_HLOCAL = 0;                  // N*C f32
constexpr size_t OFF_AGG    = 5120000;            // N*C f32
constexpr size_t OFF_DEG    = 10240000;           // N f32
constexpr size_t OFF_KEY    = 10320000;           // N u64 (keys; later overlaid by hist+tmax)
constexpr size_t OFF_SCORE  = 10480000;           // N f32
constexpr size_t OFF_SELF   = 10560000;           // N i32
constexpr size_t OFF_N2M    = 10640000;           // N i32
constexpr size_t OFF_MIDX   = 10720000;           // K i32
constexpr size_t OFF_HM     = 10728000;           // K*C f32
constexpr size_t OFF_POSM   = 11240000;           // K*3 f32
constexpr size_t OFF_Q      = 11264000;           // K*16 f32
constexpr size_t OFF_KBUF   = 11392000;           // K*16 f32
constexpr size_t OFF_EXIST  = 11520000;           // K*K u8
constexpr size_t OFF_SRCA   = 15520000;           // EALL i32
constexpr size_t OFF_DSTA   = 16288000;           // EALL i32
constexpr size_t OFF_MASKA  = 17056000;           // EALL f32
constexpr size_t OFF_AGGM   = 17824000;           // K*C f32
constexpr size_t OFF_DEGM   = 18336000;           // K f32
constexpr size_t OFF_W0     = 18344000;           // 576 f32
constexpr size_t OFF_W0NZ   = 18346304;           // i32
constexpr size_t OFF_STATE  = 18346400;           // RState + 2 edge counters
constexpr size_t OFF_CAND   = 18348000;           // cand keys / edata overlay (stream-ordered safe)
constexpr size_t OFF_RANK   = 50348000;           // N i32 rank counts
// hist (4KB) + tmax (62.5KB) overlay OFF_KEY after k_rank is done (stream-ordered)

struct RState {
    unsigned long long prefix;
    int R;
    unsigned int cand_count;
    unsigned int sel_count;
    int bin_thresh;
    unsigned int total;
    unsigned int pad;
};

// ---------------- w0nz: does the edge-independent weight (env==0 path) vanish? ----------------
__global__ void k_w0(const float* __restrict__ fc_b1, const float* __restrict__ fc_w2,
                     const float* __restrict__ fc_b2, float* __restrict__ w0, int* __restrict__ w0nz)
{
    __shared__ float hid0[64];
    __shared__ int nz;
    int tid = threadIdx.x;
    if (tid == 0) nz = 0;
    if (tid < 64) hid0[tid] = fmaxf(fc_b1[tid], 0.0f);
    __syncthreads();
    if (tid < CSH_) {
        float acc = fc_b2[tid];
        for (int k = 0; k < 64; k++) acc += hid0[k] * fc_w2[k * CSH_ + tid];
        w0[tid] = acc;
        if (acc != 0.0f) atomicOr(&nz, 1);
    }
    __syncthreads();
    if (tid == 0) *w0nz = nz;
}

// ---------------- edge prep: geometry + bessel, deg atomics, compact contributing edges ----------------
// edata layout per edge (20 f32): ef[8], sh[9], src(bits), dst(bits), msk
__global__ __launch_bounds__(256) void k_prep(
    int n_edges, const int* __restrict__ src, const int* __restrict__ dst,
    const float* __restrict__ mask, const float* __restrict__ posn,
    const int* __restrict__ w0nz, float* __restrict__ deg,
    float* __restrict__ edata, unsigned int* __restrict__ cnt)
{
    int e = blockIdx.x * 256 + threadIdx.x;
    bool valid = e < n_edges;
    int s_i = 0, d_i = 0; float msk = 0.0f;
    if (valid) {
        s_i = src[e]; d_i = dst[e];
        msk = mask ? mask[e] : 1.0f;
    }
    bool active = valid && (msk != 0.0f);

    float vx = 0.f, vy = 0.f, vz = 0.f;
    if (active) {
        vx = posn[s_i*3+0] - posn[d_i*3+0];
        vy = posn[s_i*3+1] - posn[d_i*3+1];
        vz = posn[s_i*3+2] - posn[d_i*3+2];
    }
    float r = sqrtf(vx*vx + vy*vy + vz*vz + 1e-12f);
    float invr = 1.0f / r;
    float x = vx*invr, y = vy*invr, z = vz*invr;
    const float s3 = 1.7320508075688772f, s15 = 3.872983346207417f, s5 = 2.23606797749979f;
    float sh[9];
    sh[0] = 1.0f; sh[1] = s3*x; sh[2] = s3*y; sh[3] = s3*z;
    sh[4] = s15*x*y; sh[5] = s15*y*z; sh[6] = 0.5f*s5*(3.0f*z*z - 1.0f);
    sh[7] = s15*x*z; sh[8] = 0.5f*s15*(x*x - y*y);

    float u = r * 0.2f; u = u > 1.0f ? 1.0f : u;
    float u2 = u*u, u6 = u2*u2*u2, u7 = u6*u, u8 = u7*u;
    float env = 1.0f - 28.0f*u6 + 48.0f*u7 - 21.0f*u8;
    float rc = r > 1e-9f ? r : 1e-9f;
    const float bpref = 0.6324555320336759f;      // sqrt(2/5)
    const float PIov5 = 0.6283185307179586f;
    float ef[8];
    #pragma unroll
    for (int n = 0; n < 8; n++)
        ef[n] = bpref * sinf(PIov5 * r * (float)(n + 1)) / rc * env;

    if (active) atomicAdd(&deg[s_i], msk);

    bool contrib = active && !((env == 0.0f) && (*w0nz == 0));
    int lane = threadIdx.x & 63;
    unsigned long long b = __ballot(contrib);
    int wc = __popcll(b);
    int base = 0;
    if (lane == 0 && wc) base = (int)atomicAdd(cnt, (unsigned)wc);
    base = __shfl(base, 0);
    if (contrib) {
        int slot = base + __popcll(b & ((1ull << lane) - 1ull));
        float* p = edata + (size_t)slot * 20;
        #pragma unroll
        for (int n = 0; n < 8; n++) p[n] = ef[n];
        #pragma unroll
        for (int t = 0; t < 9; t++) p[8+t] = sh[t];
        p[17] = __int_as_float(s_i);
        p[18] = __int_as_float(d_i);
        p[19] = msk;
    }
}

// ---------------- batched conv GEMM: 32 edges/block; weights read straight from L1/L2 ----------------
__global__ __launch_bounds__(256, 5) void k_convg(
    const unsigned int* __restrict__ cnt, const float* __restrict__ edata,
    const float* __restrict__ hn,
    const float* __restrict__ fc_w1, const float* __restrict__ fc_b1,
    const float* __restrict__ fc_w2, const float* __restrict__ fc_b2,
    const float* __restrict__ lin_w, float* __restrict__ agg)
{
    __shared__ float s_misc[TB_ * 12];                 // sh[9], src, msk, pad
    __shared__ float s_hid[TB_ * 68];                  // padded rows
    __shared__ float s_hd[TB_ * 64];
    __shared__ float s_tp[TB_ * 68];
    // LDS = 27136 B -> 5 blocks/CU (was 59904 -> 2)

    const int tid = threadIdx.x;
    const int jj4 = (tid & 15) * 4;
    const int eg  = tid >> 4;                          // 0..15
    const int e0 = eg, e1 = eg + 16;

    const int nheavy = (int)*cnt;
    const int nblk = (nheavy + TB_ - 1) / TB_;

    for (int blk = blockIdx.x; blk < nblk; blk += gridDim.x) {
        const int ebase = blk * TB_;
        int nE = nheavy - ebase; if (nE > TB_) nE = TB_;

        for (int idx = tid; idx < TB_ * 12; idx += 256) {
            int e = idx / 12, f = idx - 12 * e;
            float v = 0.0f;
            if (e < nE) {
                const float* p = edata + (size_t)(ebase + e) * 20;
                v = (f < 9) ? p[8 + f] : (f == 9) ? p[17] : (f == 10) ? p[19] : 0.0f;
            }
            s_misc[idx] = v;
        }
        for (int idx = tid; idx < TB_ * 64; idx += 256) {
            int e = idx >> 6, k = idx & 63;
            float hv = 0.0f, hdv = 0.0f;
            if (e < nE) {
                const float* p = edata + (size_t)(ebase + e) * 20;
                float acc = fc_b1[k];
                #pragma unroll
                for (int n = 0; n < 8; n++) acc += p[n] * fc_w1[n * 64 + k];
                hv = fmaxf(acc, 0.0f);
                int dsti = __float_as_int(p[18]);
                hdv = hn[dsti * 64 + k];
            }
            s_hid[e * 68 + k] = hv;
            s_hd[e * 64 + k] = hdv;
        }
        float m0[4] = {0.f,0.f,0.f,0.f}, m1[4] = {0.f,0.f,0.f,0.f};
        __syncthreads();

        for (int cj = 0; cj < 9; cj++) {
            const int j0 = cj * 64;

            // GEMM1: w[e][j] = b2[j] + hid[e][:] @ W2[:, j]   (W2 chunk from L1/L2)
            float a0[4], a1[4];
            #pragma unroll
            for (int q = 0; q < 4; q++) { float b = fc_b2[j0 + jj4 + q]; a0[q] = b; a1[q] = b; }
            #pragma unroll 4
            for (int k = 0; k < 64; k++) {
                float4 w4 = *reinterpret_cast<const float4*>(&fc_w2[k * CSH_ + j0 + jj4]);
                float h0 = s_hid[e0 * 68 + k], h1 = s_hid[e1 * 68 + k];
                a0[0] += h0 * w4.x; a0[1] += h0 * w4.y; a0[2] += h0 * w4.z; a0[3] += h0 * w4.w;
                a1[0] += h1 * w4.x; a1[1] += h1 * w4.y; a1[2] += h1 * w4.z; a1[3] += h1 * w4.w;
            }
            #pragma unroll
            for (int q = 0; q < 4; q++) {
                int j = j0 + jj4 + q; int c = j / 9; int si = j - 9 * c;
                s_tp[e0 * 68 + jj4 + q] = s_hd[e0 * 64 + c] * s_misc[e0 * 12 + si] * a0[q];
                s_tp[e1 * 68 + jj4 + q] = s_hd[e1 * 64 + c] * s_misc[e1 * 12 + si] * a1[q];
            }
            __syncthreads();

            // GEMM2: msg[e][o] += tp[e][:] @ lin_w_chunk[:, o]  (lin_w chunk from L1/L2)
            #pragma unroll 4
            for (int jj = 0; jj < 64; jj++) {
                float4 l4 = *reinterpret_cast<const float4*>(&lin_w[(j0 + jj) * 64 + jj4]);
                float t0 = s_tp[e0 * 68 + jj], t1 = s_tp[e1 * 68 + jj];
                m0[0] += t0 * l4.x; m0[1] += t0 * l4.y; m0[2] += t0 * l4.z; m0[3] += t0 * l4.w;
                m1[0] += t1 * l4.x; m1[1] += t1 * l4.y; m1[2] += t1 * l4.z; m1[3] += t1 * l4.w;
            }
            __syncthreads();
        }

        float mk0 = s_misc[e0 * 12 + 10], mk1 = s_misc[e1 * 12 + 10];
        if (mk0 != 0.0f) {
            int s0 = __float_as_int(s_misc[e0 * 12 + 9]);
            #pragma unroll
            for (int q = 0; q < 4; q++) atomicAdd(&agg[s0 * 64 + jj4 + q], m0[q] * mk0);
        }
        if (mk1 != 0.0f) {
            int s1 = __float_as_int(s_misc[e1 * 12 + 9]);
            #pragma unroll
            for (int q = 0; q < 4; q++) atomicAdd(&agg[s1 * 64 + jj4 + q], m1[q] * mk1);
        }
        __syncthreads();
    }
}

// ---------------- h_local = h + agg/max(deg,1) ----------------
__global__ void k_hlocal(const float* __restrict__ h, const float* __restrict__ agg,
                         const float* __restrict__ deg, float* __restrict__ h_local)
{
    int idx = blockIdx.x * 256 + threadIdx.x;
    if (idx < N_ * C_) {
        float d = deg[idx >> 6];
        h_local[idx] = h[idx] + agg[idx] / fmaxf(d, 1.0f);
    }
}

// ---------------- per-node score + composite sort key ----------------
__global__ __launch_bounds__(256) void k_score(const float* __restrict__ h_local,
    const float* __restrict__ ms_w1, const float* __restrict__ ms_b1,
    const float* __restrict__ ms_w2, const float* __restrict__ ms_b2,
    float* __restrict__ score, unsigned long long* __restrict__ key)
{
    int wid = threadIdx.x >> 6, lane = threadIdx.x & 63;
    int n = blockIdx.x * 4 + wid;
    if (n >= N_) return;
    float acc = ms_b1[lane];
    #pragma unroll
    for (int i = 0; i < 16; i++) acc += h_local[n*64 + i] * ms_w1[i*64 + lane];
    acc = fmaxf(acc, 0.0f);
    float part = acc * ms_w2[lane];
    #pragma unroll
    for (int off = 32; off > 0; off >>= 1) part += __shfl_xor(part, off);
    if (lane == 0) {
        float s = part + ms_b2[0];
        float sc = 1.0f / (1.0f + expf(-s));
        score[n] = sc;
        key[n] = ((unsigned long long)__float_as_uint(sc) << 32)
               | (unsigned long long)(0xFFFFFFFFu - (unsigned)n);
    }
}

// ---------------- exact top-K rank counting, split over 16 j-segments ----------------
__global__ void k_rank(const unsigned long long* __restrict__ key, int* __restrict__ rankcnt)
{
    __shared__ unsigned long long tile[256];
    int i = blockIdx.x * 256 + threadIdx.x;
    int seg = blockIdx.y;
    int lo = seg * 1250, hi = lo + 1250;
    unsigned long long my = (i < N_) ? key[i] : ~0ull;
    int cnt = 0;
    for (int t0 = lo; t0 < hi; t0 += 256) {
        int idx = t0 + threadIdx.x;
        tile[threadIdx.x] = (idx < hi) ? key[idx] : 0ull;
        __syncthreads();
        int lim = hi - t0; if (lim > 256) lim = 256;
        for (int j = 0; j < lim; j++) cnt += (tile[j] > my) ? 1 : 0;
        __syncthreads();
    }
    if (i < N_ && cnt) atomicAdd(&rankcnt[i], cnt);
}

__global__ void k_rank_fin(const int* __restrict__ rankcnt, const float* __restrict__ score,
                           int* __restrict__ selflag, float* __restrict__ m_out)
{
    int i = blockIdx.x * 256 + threadIdx.x;
    if (i >= N_) return;
    int sel = (rankcnt[i] < K_) ? 1 : 0;
    selflag[i] = sel;
    m_out[i] = sel ? score[i] : 0.0f;
}

// ---------------- single-block prefix scan: node2m + master_idx ----------------
__global__ void k_scan(const int* __restrict__ selflag, int* __restrict__ node2m,
                       int* __restrict__ midx)
{
    __shared__ int ssum[1024];
    int tid = threadIdx.x;
    int start = tid * 20;
    int c = 0;
    for (int k = 0; k < 20; k++) { int idx = start + k; if (idx < N_) c += selflag[idx]; }
    ssum[tid] = c;
    __syncthreads();
    for (int off = 1; off < 1024; off <<= 1) {
        int v = (tid >= off) ? ssum[tid - off] : 0;
        __syncthreads();
        ssum[tid] += v;
        __syncthreads();
    }
    int run = ssum[tid] - c;
    for (int k = 0; k < 20; k++) {
        int idx = start + k;
        if (idx < N_) {
            if (selflag[idx]) { node2m[idx] = run; midx[run] = idx; run++; }
            else node2m[idx] = -1;
        }
    }
}

// ---------------- gather master nodes + q/k projections ----------------
__global__ void k_master(const int* __restrict__ midx, const float* __restrict__ h_local,
    const float* __restrict__ pos, const float* __restrict__ vg_wq, const float* __restrict__ vg_wk,
    float* __restrict__ h_m, float* __restrict__ pos_m,
    float* __restrict__ qbuf, float* __restrict__ kbuf)
{
    int mi = blockIdx.x;
    int lane = threadIdx.x;
    int node = midx[mi];
    h_m[mi*64 + lane] = h_local[node*64 + lane];
    if (lane < 3) pos_m[mi*3 + lane] = pos[node*3 + lane];
    if (lane < 32) {
        int j = lane & 15;
        const float* wm = (lane < 16) ? vg_wq : vg_wk;
        float acc = 0.0f;
        #pragma unroll
        for (int i = 0; i < 16; i++) acc += h_local[node*64 + i] * wm[i*16 + j];
        if (lane < 16) qbuf[mi*16 + j] = acc; else kbuf[mi*16 + j] = acc;
    }
}

// ---------------- map edges to master ids, build exist matrix ----------------
__global__ void k_exist(const int* __restrict__ src, const int* __restrict__ dst,
    const int* __restrict__ node2m, int* __restrict__ src_all, int* __restrict__ dst_all,
    float* __restrict__ mask_all, unsigned char* __restrict__ exist)
{
    int e = blockIdx.x * 256 + threadIdx.x;
    if (e >= E_) return;
    int sm = node2m[src[e]], dm = node2m[dst[e]];
    bool em = (sm >= 0) && (dm >= 0);
    int smc = sm >= 0 ? sm : 0;
    int dmc = dm >= 0 ? dm : 0;
    src_all[e] = smc; dst_all[e] = dmc; mask_all[e] = em ? 1.0f : 0.0f;
    if (em) exist[smc * K_ + dmc] = 1;
}

// ---------------- attention pass 1: Av + per-tile max + 1024-bin candidate histogram ----------------
constexpr int NTILE_ = (K_ / 16) * (K_ / 16);   // 15625
__global__ __launch_bounds__(256) void k_attn1(const float* __restrict__ qbuf,
    const float* __restrict__ kbuf, const unsigned char* __restrict__ exist,
    float* __restrict__ Av, float* __restrict__ tmax, unsigned int* __restrict__ hist)
{
    constexpr int TBK = K_ / 16;
    __shared__ float sq[16][17], sk[16][17];
    __shared__ unsigned int lh[1024];
    __shared__ float wmax[4];
    int tid = threadIdx.x;
    for (int b = tid; b < 1024; b += 256) lh[b] = 0;

    for (int t = blockIdx.x; t < NTILE_; t += gridDim.x) {
        int bi = t / TBK, bj = t % TBK;
        int i0 = bi * 16, j0 = bj * 16;
        int r = tid >> 4, c = tid & 15;
        __syncthreads();                     // protect sq/sk from previous iter readers
        sq[r][c] = qbuf[(i0 + r) * 16 + c];
        sk[r][c] = kbuf[(j0 + r) * 16 + c];
        __syncthreads();
        int ti = tid >> 4, tj = tid & 15;
        float dot = 0.0f;
        #pragma unroll
        for (int cc = 0; cc < 16; cc++) dot += sq[ti][cc] * sk[tj][cc];
        float attn = 1.0f / (1.0f + expf(-dot * 0.25f));
        int gi = i0 + ti, gj = j0 + tj;
        int flat = gi * K_ + gj;
        bool ex = (exist[flat] != 0) || (gi == gj);
        bool av = (!ex) && (attn > 0.5f);
        Av[flat] = av ? 1.0f : 0.0f;
        float cv = av ? attn : 0.0f;
        if (av) {
            unsigned bin = (__float_as_uint(attn) - 0x3F000000u) >> 13;
            if (bin > 1023u) bin = 1023u;
            atomicAdd(&lh[bin], 1u);
        }
        float wm = cv;
        #pragma unroll
        for (int off = 32; off > 0; off >>= 1) wm = fmaxf(wm, __shfl_xor(wm, off));
        int wid = tid >> 6, lane = tid & 63;
        if (lane == 0) wmax[wid] = wm;
        __syncthreads();
        if (tid == 0) tmax[t] = fmaxf(fmaxf(wmax[0], wmax[1]), fmaxf(wmax[2], wmax[3]));
    }
    __syncthreads();
    for (int b = tid; b < 1024; b += 256) {
        unsigned v = lh[b];
        if (v) atomicAdd(&hist[b], v);
    }
}

// ---------------- pick bin threshold B: suffix(B) >= R = min(EV, total) ----------------
__global__ __launch_bounds__(1024) void k_bsel(const unsigned int* __restrict__ hist, RState* st)
{
    __shared__ unsigned int h[1024];
    int tid = threadIdx.x;
    h[tid] = hist[tid];
    __syncthreads();
    for (int off = 1; off < 1024; off <<= 1) {
        unsigned v = (tid + off < 1024) ? h[tid + off] : 0u;
        __syncthreads();
        h[tid] += v;
        __syncthreads();
    }
    unsigned total = h[0];
    int R = (total < (unsigned)EV_) ? (int)total : EV_;
    if (tid == 0) {
        st->R = R;
        st->total = total;
        st->cand_count = 0;
        st->sel_count = 0;
        if (R == 0) st->bin_thresh = 1024;
    }
    __syncthreads();
    if (R > 0) {
        unsigned hi = (tid == 1023) ? 0u : h[tid + 1];
        if ((int)h[tid] >= R && (int)hi < R) st->bin_thresh = tid;
    }
}

// ---------------- attention pass 2: store candidate keys above bin threshold ----------------
__global__ __launch_bounds__(256) void k_attn2(const float* __restrict__ qbuf,
    const float* __restrict__ kbuf, const unsigned char* __restrict__ exist,
    const float* __restrict__ tmax, RState* st, unsigned long long* __restrict__ cand)
{
    constexpr int TBK = K_ / 16;
    __shared__ float sq[16][17], sk[16][17];
    __shared__ int wb[4];
    __shared__ int bb;
    int tid = threadIdx.x;
    unsigned tbits = 0x3F000000u + ((unsigned)st->bin_thresh << 13);

    for (int t = blockIdx.x; t < NTILE_; t += gridDim.x) {
        if (__float_as_uint(tmax[t]) < tbits) continue;
        int bi = t / TBK, bj = t % TBK;
        int i0 = bi * 16, j0 = bj * 16;
        int r = tid >> 4, c = tid & 15;
        __syncthreads();
        sq[r][c] = qbuf[(i0 + r) * 16 + c];
        sk[r][c] = kbuf[(j0 + r) * 16 + c];
        __syncthreads();
        int ti = tid >> 4, tj = tid & 15;
        float dot = 0.0f;
        #pragma unroll
        for (int cc = 0; cc < 16; cc++) dot += sq[ti][cc] * sk[tj][cc];
        float attn = 1.0f / (1.0f + expf(-dot * 0.25f));
        int gi = i0 + ti, gj = j0 + tj;
        int flat = gi * K_ + gj;
        bool ex = (exist[flat] != 0) || (gi == gj);
        bool store = (!ex) && (attn > 0.5f) && (__float_as_uint(attn) >= tbits);

        unsigned long long keyv = ((unsigned long long)__float_as_uint(attn) << 32)
                                | (unsigned long long)(0xFFFFFFFFu - (unsigned)flat);
        int wid = tid >> 6, lane = tid & 63;
        unsigned long long b = __ballot(store);
        int wc = __popcll(b);
        if (lane == 0) wb[wid] = wc;
        __syncthreads();
        if (tid == 0) {
            int s = 0;
            for (int w = 0; w < 4; w++) { int cc2 = wb[w]; wb[w] = s; s += cc2; }
            bb = s ? (int)atomicAdd(&st->cand_count, (unsigned)s) : 0;
        }
        __syncthreads();
        if (store) {
            int slot = bb + wb[wid] + __popcll(b & ((1ull << lane) - 1ull));
            cand[slot] = keyv;
        }
    }
}

// ---------------- single-block 8-pass radix select over stored candidates ----------------
__global__ __launch_bounds__(1024) void k_radix1b(RState* st, const unsigned long long* __restrict__ cand)
{
    __shared__ unsigned int lh[256];
    __shared__ unsigned int suf[256];
    __shared__ unsigned long long s_pref;
    __shared__ int s_R;
    int tid = threadIdx.x;
    int n = (int)st->cand_count;
    int R = st->R;
    if (tid == 0) { s_pref = 0ull; s_R = R; st->sel_count = 0; }
    __syncthreads();
    if (R <= 0) { if (tid == 0) st->prefix = ~0ull; return; }

    for (int p = 0; p < 8; p++) {
        if (tid < 256) lh[tid] = 0;
        __syncthreads();
        unsigned long long pref = s_pref;
        int sh_d = 56 - 8 * p;
        for (int i = tid; i < n; i += 1024) {
            unsigned long long kv = cand[i];
            bool ok = (p == 0) || ((kv >> (sh_d + 8)) == (pref >> (sh_d + 8)));
            if (ok) atomicAdd(&lh[(unsigned)((kv >> sh_d) & 255ull)], 1u);
        }
        __syncthreads();
        if (tid < 256) suf[tid] = lh[tid];
        __syncthreads();
        for (int off = 1; off < 256; off <<= 1) {
            unsigned v = 0;
            if (tid < 256 && tid + off < 256) v = suf[tid + off];
            __syncthreads();
            if (tid < 256) suf[tid] += v;
            __syncthreads();
        }
        if (tid < 256) {
            int Rc = s_R;
            unsigned hi = (tid == 255) ? 0u : suf[tid + 1];
            if ((int)suf[tid] >= Rc && (int)hi < Rc) {
                s_pref = pref | ((unsigned long long)(unsigned)tid << sh_d);
                s_R = Rc - (int)hi;
            }
        }
        __syncthreads();
    }
    if (tid == 0) st->prefix = s_pref;
}

// ---------------- emit selected virtual edges ----------------
__global__ void k_vsel(RState* st, const unsigned long long* __restrict__ cand,
                       int* __restrict__ src_all, int* __restrict__ dst_all,
                       float* __restrict__ mask_all)
{
    int n = (int)st->cand_count;
    unsigned long long T = st->prefix;
    int lane = threadIdx.x & 63;
    int stride = gridDim.x * 256;
    for (int start = blockIdx.x * 256; start < n; start += stride) {
        int idx = start + threadIdx.x;
        bool sel = (idx < n) && (cand[idx] >= T);
        unsigned long long b = __ballot(sel);
        int wc = __popcll(b);
        int basep = 0;
        if (lane == 0 && wc) basep = (int)atomicAdd(&st->sel_count, (unsigned)wc);
        basep = __shfl(basep, 0);
        if (sel) {
            int slot = basep + __popcll(b & ((1ull << lane) - 1ull));
            if (slot < EV_) {
                unsigned flat = 0xFFFFFFFFu - (unsigned)(cand[idx] & 0xFFFFFFFFull);
                src_all[E_ + slot] = (int)(flat / (unsigned)K_);
                dst_all[E_ + slot] = (int)(flat % (unsigned)K_);
                mask_all[E_ + slot] = 1.0f;
            }
        }
    }
}

// ---------------- final mixing ----------------
__global__ void k_final(const float* __restrict__ h_local, const int* __restrict__ node2m,
    const float* __restrict__ aggm, const float* __restrict__ degm, const float* __restrict__ h_m,
    const float* __restrict__ m_out, float* __restrict__ out_h)
{
    int idx = blockIdx.x * 256 + threadIdx.x;
    if (idx >= N_ * C_) return;
    int i = idx >> 6, c = idx & 63;
    float mval = m_out[i];
    int mi = node2m[i];
    float hh = 0.0f;
    if (mi >= 0) hh = aggm[mi*64 + c] / fmaxf(degm[mi], 1.0f) + h_m[mi*64 + c];
    out_h[idx] = (1.0f - mval) * h_local[idx] + mval * hh;
}

__global__ void k_pos(const float* __restrict__ pos, float* __restrict__ out_pos)
{
    int idx = blockIdx.x * 256 + threadIdx.x;
    if (idx < N_ * 3) out_pos[idx] = pos[idx];
}

// ---------------- launch ----------------
extern "C" void kernel_launch(void* const* d_in, const int* in_sizes, int n_in,
                              void* d_out, int out_size, void* d_ws, size_t ws_size,
                              hipStream_t stream)
{
    (void)in_sizes; (void)n_in; (void)out_size; (void)ws_size;
    const float* h     = (const float*)d_in[0];
    const float* pos   = (const float*)d_in[1];
    const int*   eidx  = (const int*)d_in[2];
    const float* fc_w1 = (const float*)d_in[3];
    const float* fc_b1 = (const float*)d_in[4];
    const float* fc_w2 = (const float*)d_in[5];
    const float* fc_b2 = (const float*)d_in[6];
    const float* lin_w = (const float*)d_in[7];
    const float* ms_w1 = (const float*)d_in[8];
    const float* ms_b1 = (const float*)d_in[9];
    const float* ms_w2 = (const float*)d_in[10];
    const float* ms_b2 = (const float*)d_in[11];
    const float* vg_wq = (const float*)d_in[12];
    const float* vg_wk = (const float*)d_in[13];

    char* ws = (char*)d_ws;
    float* h_local = (float*)(ws + OFF_HLOCAL);
    float* agg     = (float*)(ws + OFF_AGG);
    float* deg     = (float*)(ws + OFF_DEG);
    unsigned long long* key = (unsigned long long*)(ws + OFF_KEY);
    float* score   = (float*)(ws + OFF_SCORE);
    int*   selflag = (int*)(ws + OFF_SELF);
    int*   node2m  = (int*)(ws + OFF_N2M);
    int*   midx    = (int*)(ws + OFF_MIDX);
    float* h_m     = (float*)(ws + OFF_HM);
    float* pos_m   = (float*)(ws + OFF_POSM);
    float* qbuf    = (float*)(ws + OFF_Q);
    float* kbuf    = (float*)(ws + OFF_KBUF);
    unsigned char* exist = (unsigned char*)(ws + OFF_EXIST);
    int*   src_all = (int*)(ws + OFF_SRCA);
    int*   dst_all = (int*)(ws + OFF_DSTA);
    float* mask_all = (float*)(ws + OFF_MASKA);
    float* aggm    = (float*)(ws + OFF_AGGM);
    float* degm    = (float*)(ws + OFF_DEGM);
    float* w0      = (float*)(ws + OFF_W0);
    int*   w0nz    = (int*)(ws + OFF_W0NZ);
    RState* st     = (RState*)(ws + OFF_STATE);
    unsigned int* cnt0 = (unsigned int*)(ws + OFF_STATE + sizeof(RState));
    unsigned int* cnt1 = cnt0 + 1;
    unsigned long long* cand = (unsigned long long*)(ws + OFF_CAND);
    float* edata   = (float*)(ws + OFF_CAND);        // overlays cand (stream-ordered: safe)
    int*   rankcnt = (int*)(ws + OFF_RANK);
    // hist + tmax overlay the key region (used only after k_rank completes)
    unsigned int* hist = (unsigned int*)(ws + OFF_KEY);
    float* tmax    = (float*)(ws + OFF_KEY + 4096);

    float* out_h   = (float*)d_out;
    float* out_pos = out_h + (size_t)N_ * C_;
    float* out_av  = out_pos + (size_t)N_ * 3;
    float* out_m   = out_av + (size_t)K_ * K_;

    // zero-init (d_ws is poisoned with 0xAA before every call)
    hipMemsetAsync(ws + OFF_AGG, 0, 5200000, stream);                 // agg + deg
    hipMemsetAsync(ws + OFF_EXIST, 0, 4000000, stream);               // exist
    hipMemsetAsync(ws + OFF_AGGM, 0, 520000, stream);                 // aggm + degm
    hipMemsetAsync(ws + OFF_STATE, 0, sizeof(RState) + 8, stream);    // state + edge counters
    hipMemsetAsync(ws + OFF_RANK, 0, (size_t)N_ * 4, stream);         // rank counts
    hipMemsetAsync(ws + OFF_SRCA + (size_t)E_*4, 0, (size_t)EV_*4, stream);
    hipMemsetAsync(ws + OFF_DSTA + (size_t)E_*4, 0, (size_t)EV_*4, stream);
    hipMemsetAsync(ws + OFF_MASKA + (size_t)E_*4, 0, (size_t)EV_*4, stream);

    k_w0<<<1, 576, 0, stream>>>(fc_b1, fc_w2, fc_b2, w0, w0nz);

    // ---- conv 1 on full graph ----
    k_prep<<<E_ / 256, 256, 0, stream>>>(E_, eidx, eidx + E_, nullptr, pos, w0nz, deg, edata, cnt0);
    k_convg<<<2048, 256, 0, stream>>>(cnt0, edata, h, fc_w1, fc_b1, fc_w2, fc_b2, lin_w, agg);

    k_hlocal<<<(N_ * C_ + 255) / 256, 256, 0, stream>>>(h, agg, deg, h_local);

    k_score<<<(N_ + 3) / 4, 256, 0, stream>>>(h_local, ms_w1, ms_b1, ms_w2, ms_b2, score, key);

    k_rank<<<dim3((N_ + 255) / 256, 16), 256, 0, stream>>>(key, rankcnt);
    k_rank_fin<<<(N_ + 255) / 256, 256, 0, stream>>>(rankcnt, score, selflag, out_m);

    k_scan<<<1, 1024, 0, stream>>>(selflag, node2m, midx);

    k_master<<<K_, 64, 0, stream>>>(midx, h_local, pos, vg_wq, vg_wk, h_m, pos_m, qbuf, kbuf);

    k_exist<<<(E_ + 255) / 256, 256, 0, stream>>>(eidx, eidx + E_, node2m,
        src_all, dst_all, mask_all, exist);

    // ---- virtual edge selection (histogram prefilter + small exact radix) ----
    hipMemsetAsync(ws + OFF_KEY, 0, 4096, stream);                    // hist (key region is free now)
    k_attn1<<<128, 256, 0, stream>>>(qbuf, kbuf, exist, out_av, tmax, hist);
    k_bsel<<<1, 1024, 0, stream>>>(hist, st);
    k_attn2<<<128, 256, 0, stream>>>(qbuf, kbuf, exist, tmax, st, cand);
    k_radix1b<<<1, 1024, 0, stream>>>(st, cand);
    k_vsel<<<64, 256, 0, stream>>>(st, cand, src_all, dst_all, mask_all);

    // ---- conv 2 on master graph (real + virtual edges) ----
    k_prep<<<EALL_ / 256, 256, 0, stream>>>(EALL_, src_all, dst_all, mask_all, pos_m, w0nz,
                                            degm, edata, cnt1);
    k_convg<<<2048, 256, 0, stream>>>(cnt1, edata, h_m, fc_w1, fc_b1, fc_w2, fc_b2, lin_w, aggm);

    k_final<<<(N_ * C_ + 255) / 256, 256, 0, stream>>>(h_local, node2m, aggm, degm, h_m, out_m, out_h);

    k_pos<<<(N_ * 3 + 255) / 256, 256, 0, stream>>>(pos, out_pos);
}

// Round 4
// 763.992 us; speedup vs baseline: 2.0735x; 1.2077x over previous
//
#include <hip/hip_runtime.h>
#include <stdint.h>

// ---------------- problem constants ----------------
constexpr int N_   = 20000;
constexpr int E_   = 160000;
constexpr int C_   = 64;
constexpr int K_   = 2000;
constexpr int EV_  = 32000;
constexpr int EALL_ = E_ + EV_;          // 192000
constexpr int CSH_ = 576;                // C*SH
constexpr int TB_  = 48;                 // edges per block in batched conv

// ---------------- workspace layout (bytes) ----------------
// [ zero block: one memset covers OFF_AGG .. OFF_STATE+256 ]
constexpr size_t OFF_AGG    = 0;                  // N*C f32     5,120,000
constexpr size_t OFF_DEG    = 5120000;            // N f32          80,000
constexpr size_t OFF_AGGM   = 5200000;            // K*C f32       512,000
constexpr size_t OFF_DEGM   = 5712000;            // K f32           8,000
constexpr size_t OFF_RANK   = 5720000;            // N i32          80,000
constexpr size_t OFF_MASKA  = 5800000;            // EALL f32      768,000
constexpr size_t OFF_EXIST  = 6568000;            // K*K u8      4,000,000
constexpr size_t OFF_HIST   = 10568000;           // 1024 u32        4,096
constexpr size_t OFF_STATE  = 10572096;           // RState + counters 256
constexpr size_t ZERO_BYTES = 10572352;
// [ non-zero region ]
constexpr size_t OFF_HLOCAL = 10572352;           // N*C f32
constexpr size_t OFF_KEY    = 15692352;           // N u64
constexpr size_t OFF_SCORE  = 15852352;           // N f32
constexpr size_t OFF_N2M    = 15932352;           // N i32
constexpr size_t OFF_MIDX   = 16012352;           // K i32
constexpr size_t OFF_HM     = 16020352;           // K*C f32
constexpr size_t OFF_POSM   = 16532352;           // K*3 f32
constexpr size_t OFF_Q      = 16556352;           // K*16 f32
constexpr size_t OFF_KBUF   = 16684352;           // K*16 f32
constexpr size_t OFF_SRCA   = 16812352;           // EALL i32
constexpr size_t OFF_DSTA   = 17580352;           // EALL i32
constexpr size_t OFF_TMAX   = 18348352;           // 15625 f32 (+pad)
constexpr size_t OFF_CAND   = 18410880;           // 32 MB: cand keys / edata overlay
// total ~50.4 MB

struct RState {
    unsigned long long prefix;
    int R;
    unsigned int cand_count;
    unsigned int sel_count;
    int bin_thresh;
    unsigned int total;
    unsigned int pad;
};
// state area: RState at +0, cnt0 at +64, cnt1 at +68, w0nz at +72

// ---------------- w0nz: does the edge-independent weight (env==0 path) vanish? ----------------
__global__ void k_w0(const float* __restrict__ fc_b1, const float* __restrict__ fc_w2,
                     const float* __restrict__ fc_b2, int* __restrict__ w0nz)
{
    __shared__ float hid0[64];
    __shared__ int nz;
    int tid = threadIdx.x;
    if (tid == 0) nz = 0;
    if (tid < 64) hid0[tid] = fmaxf(fc_b1[tid], 0.0f);
    __syncthreads();
    if (tid < CSH_) {
        float acc = fc_b2[tid];
        for (int k = 0; k < 64; k++) acc += hid0[k] * fc_w2[k * CSH_ + tid];
        if (acc != 0.0f) atomicOr(&nz, 1);
    }
    __syncthreads();
    if (tid == 0) *w0nz = nz;
}

// ---------------- edge prep: geometry + bessel, deg atomics, compact contributing edges ----------------
// edata layout per edge (20 f32): ef[8], sh[9], src(bits), dst(bits), msk
__global__ __launch_bounds__(256) void k_prep(
    int n_edges, const int* __restrict__ src, const int* __restrict__ dst,
    const float* __restrict__ mask, const float* __restrict__ posn,
    const int* __restrict__ w0nz, float* __restrict__ deg,
    float* __restrict__ edata, unsigned int* __restrict__ cnt)
{
    int e = blockIdx.x * 256 + threadIdx.x;
    bool valid = e < n_edges;
    int s_i = 0, d_i = 0; float msk = 0.0f;
    if (valid) {
        msk = mask ? mask[e] : 1.0f;
        if (msk != 0.0f) { s_i = src[e]; d_i = dst[e]; }
    }
    bool active = valid && (msk != 0.0f);

    float vx = 0.f, vy = 0.f, vz = 0.f;
    if (active) {
        vx = posn[s_i*3+0] - posn[d_i*3+0];
        vy = posn[s_i*3+1] - posn[d_i*3+1];
        vz = posn[s_i*3+2] - posn[d_i*3+2];
    }
    float r = sqrtf(vx*vx + vy*vy + vz*vz + 1e-12f);
    float invr = 1.0f / r;
    float x = vx*invr, y = vy*invr, z = vz*invr;
    const float s3 = 1.7320508075688772f, s15 = 3.872983346207417f, s5 = 2.23606797749979f;
    float sh[9];
    sh[0] = 1.0f; sh[1] = s3*x; sh[2] = s3*y; sh[3] = s3*z;
    sh[4] = s15*x*y; sh[5] = s15*y*z; sh[6] = 0.5f*s5*(3.0f*z*z - 1.0f);
    sh[7] = s15*x*z; sh[8] = 0.5f*s15*(x*x - y*y);

    float u = r * 0.2f; u = u > 1.0f ? 1.0f : u;
    float u2 = u*u, u6 = u2*u2*u2, u7 = u6*u, u8 = u7*u;
    float env = 1.0f - 28.0f*u6 + 48.0f*u7 - 21.0f*u8;
    float rc = r > 1e-9f ? r : 1e-9f;
    const float bpref = 0.6324555320336759f;      // sqrt(2/5)
    const float PIov5 = 0.6283185307179586f;
    float ef[8];
    #pragma unroll
    for (int n = 0; n < 8; n++)
        ef[n] = bpref * sinf(PIov5 * r * (float)(n + 1)) / rc * env;

    if (active) atomicAdd(&deg[s_i], msk);

    bool contrib = active && !((env == 0.0f) && (*w0nz == 0));
    int lane = threadIdx.x & 63;
    unsigned long long b = __ballot(contrib);
    int wc = __popcll(b);
    int base = 0;
    if (lane == 0 && wc) base = (int)atomicAdd(cnt, (unsigned)wc);
    base = __shfl(base, 0);
    if (contrib) {
        int slot = base + __popcll(b & ((1ull << lane) - 1ull));
        float* p = edata + (size_t)slot * 20;
        #pragma unroll
        for (int n = 0; n < 8; n++) p[n] = ef[n];
        #pragma unroll
        for (int t = 0; t < 9; t++) p[8+t] = sh[t];
        p[17] = __int_as_float(s_i);
        p[18] = __int_as_float(d_i);
        p[19] = msk;
    }
}

// ---------------- batched conv GEMM: 48 edges/block, thread = 3 edges x 4 outputs ----------------
// LDS: misc 2304 + hid 13056 + hd 12288 + tp 13056 + w 16384 = 57088 B -> 2 blocks/CU
__global__ __launch_bounds__(256, 2) void k_convg(
    const unsigned int* __restrict__ cnt, const float* __restrict__ edata,
    const float* __restrict__ hn,
    const float* __restrict__ fc_w1, const float* __restrict__ fc_b1,
    const float* __restrict__ fc_w2, const float* __restrict__ fc_b2,
    const float* __restrict__ lin_w, float* __restrict__ agg)
{
    __shared__ float s_misc[TB_ * 12];
    __shared__ float s_hid[TB_ * 68];
    __shared__ float s_hd[TB_ * 64];
    __shared__ float s_tp[TB_ * 68];
    __shared__ __align__(16) float s_w[4096];      // w2 chunk, then lin_w chunk

    const int tid = threadIdx.x;
    const int oq = (tid & 15) * 4;                 // output/j quad
    const int eg = tid >> 4;                       // 0..15

    const int nheavy = (int)*cnt;
    const int nblk = (nheavy + TB_ - 1) / TB_;

    for (int blk = blockIdx.x; blk < nblk; blk += gridDim.x) {
        const int ebase = blk * TB_;
        int nE = nheavy - ebase; if (nE > TB_) nE = TB_;

        // stage misc (sh, src, msk)
        for (int idx = tid; idx < TB_ * 12; idx += 256) {
            int e = idx / 12, f = idx - 12 * e;
            float v = 0.0f;
            if (e < nE) {
                const float* p = edata + (size_t)(ebase + e) * 20;
                v = (f < 9) ? p[8 + f] : (f == 9) ? p[17] : (f == 10) ? p[19] : 0.0f;
            }
            s_misc[idx] = v;
        }
        // hid = relu(ef @ W1 + b1); gather h[dst]
        for (int idx = tid; idx < TB_ * 64; idx += 256) {
            int e = idx >> 6, k = idx & 63;
            float hv = 0.0f, hdv = 0.0f;
            if (e < nE) {
                const float* p = edata + (size_t)(ebase + e) * 20;
                float acc = fc_b1[k];
                #pragma unroll
                for (int n = 0; n < 8; n++) acc += p[n] * fc_w1[n * 64 + k];
                hv = fmaxf(acc, 0.0f);
                int dsti = __float_as_int(p[18]);
                hdv = hn[dsti * 64 + k];
            }
            s_hid[e * 68 + k] = hv;
            s_hd[e * 64 + k] = hdv;
        }
        float acc0[4] = {0,0,0,0}, acc1[4] = {0,0,0,0}, acc2[4] = {0,0,0,0};
        __syncthreads();

        for (int cj = 0; cj < 9; cj++) {
            const int j0 = cj * 64;
            // stage w2 chunk [k][j]
            for (int i4 = tid; i4 < 1024; i4 += 256) {
                int k = i4 >> 4, q4 = (i4 & 15) * 4;
                *reinterpret_cast<float4*>(&s_w[k * 64 + q4]) =
                    *reinterpret_cast<const float4*>(&fc_w2[k * CSH_ + j0 + q4]);
            }
            __syncthreads();

            // GEMM1: w[e][j] for 3 edges x 4 j's
            float a0[4], a1[4], a2[4];
            #pragma unroll
            for (int p = 0; p < 4; p++) { float b = fc_b2[j0 + oq + p]; a0[p]=b; a1[p]=b; a2[p]=b; }
            #pragma unroll 4
            for (int k = 0; k < 64; k++) {
                float4 w4 = *reinterpret_cast<const float4*>(&s_w[k * 64 + oq]);
                float h0 = s_hid[eg * 68 + k];
                float h1 = s_hid[(eg + 16) * 68 + k];
                float h2 = s_hid[(eg + 32) * 68 + k];
                a0[0]+=h0*w4.x; a0[1]+=h0*w4.y; a0[2]+=h0*w4.z; a0[3]+=h0*w4.w;
                a1[0]+=h1*w4.x; a1[1]+=h1*w4.y; a1[2]+=h1*w4.z; a1[3]+=h1*w4.w;
                a2[0]+=h2*w4.x; a2[1]+=h2*w4.y; a2[2]+=h2*w4.z; a2[3]+=h2*w4.w;
            }
            // tp = h_dst[c] * sh[si] * w
            #pragma unroll
            for (int p = 0; p < 4; p++) {
                int j = j0 + oq + p; int c = j / 9; int si = j - 9 * c;
                s_tp[eg * 68 + oq + p]        = s_hd[eg * 64 + c]        * s_misc[eg * 12 + si]        * a0[p];
                s_tp[(eg + 16) * 68 + oq + p] = s_hd[(eg + 16) * 64 + c] * s_misc[(eg + 16) * 12 + si] * a1[p];
                s_tp[(eg + 32) * 68 + oq + p] = s_hd[(eg + 32) * 64 + c] * s_misc[(eg + 32) * 12 + si] * a2[p];
            }
            __syncthreads();

            // stage lin_w chunk [jj][o] into same buffer
            for (int i4 = tid; i4 < 1024; i4 += 256) {
                *reinterpret_cast<float4*>(&s_w[i4 * 4]) =
                    *reinterpret_cast<const float4*>(&lin_w[j0 * 64 + i4 * 4]);
            }
            __syncthreads();

            // GEMM2: msg[e][o] += tp[e][:] @ lin_w_chunk[:, o]
            #pragma unroll 4
            for (int jj = 0; jj < 64; jj++) {
                float4 l4 = *reinterpret_cast<const float4*>(&s_w[jj * 64 + oq]);
                float t0 = s_tp[eg * 68 + jj];
                float t1 = s_tp[(eg + 16) * 68 + jj];
                float t2 = s_tp[(eg + 32) * 68 + jj];
                acc0[0]+=t0*l4.x; acc0[1]+=t0*l4.y; acc0[2]+=t0*l4.z; acc0[3]+=t0*l4.w;
                acc1[0]+=t1*l4.x; acc1[1]+=t1*l4.y; acc1[2]+=t1*l4.z; acc1[3]+=t1*l4.w;
                acc2[0]+=t2*l4.x; acc2[1]+=t2*l4.y; acc2[2]+=t2*l4.z; acc2[3]+=t2*l4.w;
            }
            __syncthreads();
        }

        // emit
        {
            float mk = s_misc[eg * 12 + 10];
            if (mk != 0.0f) {
                int s = __float_as_int(s_misc[eg * 12 + 9]);
                #pragma unroll
                for (int p = 0; p < 4; p++) atomicAdd(&agg[s * 64 + oq + p], acc0[p] * mk);
            }
            mk = s_misc[(eg + 16) * 12 + 10];
            if (mk != 0.0f) {
                int s = __float_as_int(s_misc[(eg + 16) * 12 + 9]);
                #pragma unroll
                for (int p = 0; p < 4; p++) atomicAdd(&agg[s * 64 + oq + p], acc1[p] * mk);
            }
            mk = s_misc[(eg + 32) * 12 + 10];
            if (mk != 0.0f) {
                int s = __float_as_int(s_misc[(eg + 32) * 12 + 9]);
                #pragma unroll
                for (int p = 0; p < 4; p++) atomicAdd(&agg[s * 64 + oq + p], acc2[p] * mk);
            }
        }
        __syncthreads();
    }
}

// ---------------- h_local + score + sort key (merged) ----------------
__global__ __launch_bounds__(256) void k_hlscore(const float* __restrict__ h,
    const float* __restrict__ agg, const float* __restrict__ deg,
    const float* __restrict__ ms_w1, const float* __restrict__ ms_b1,
    const float* __restrict__ ms_w2, const float* __restrict__ ms_b2,
    float* __restrict__ h_local, float* __restrict__ score, unsigned long long* __restrict__ key)
{
    int wid = threadIdx.x >> 6, lane = threadIdx.x & 63;
    int n = blockIdx.x * 4 + wid;
    if (n >= N_) return;
    float d = fmaxf(deg[n], 1.0f);
    float hl = h[n*64 + lane] + agg[n*64 + lane] / d;
    h_local[n*64 + lane] = hl;
    float acc = ms_b1[lane];
    #pragma unroll
    for (int i = 0; i < 16; i++) acc += __shfl(hl, i) * ms_w1[i*64 + lane];
    acc = fmaxf(acc, 0.0f);
    float part = acc * ms_w2[lane];
    #pragma unroll
    for (int off = 32; off > 0; off >>= 1) part += __shfl_xor(part, off);
    if (lane == 0) {
        float s = part + ms_b2[0];
        float sc = 1.0f / (1.0f + expf(-s));
        score[n] = sc;
        key[n] = ((unsigned long long)__float_as_uint(sc) << 32)
               | (unsigned long long)(0xFFFFFFFFu - (unsigned)n);
    }
}

// ---------------- exact top-K rank counting, split over 16 j-segments ----------------
__global__ void k_rank(const unsigned long long* __restrict__ key, int* __restrict__ rankcnt)
{
    __shared__ unsigned long long tile[256];
    int i = blockIdx.x * 256 + threadIdx.x;
    int seg = blockIdx.y;
    int lo = seg * 1250, hi = lo + 1250;
    unsigned long long my = (i < N_) ? key[i] : ~0ull;
    int cnt = 0;
    for (int t0 = lo; t0 < hi; t0 += 256) {
        int idx = t0 + threadIdx.x;
        tile[threadIdx.x] = (idx < hi) ? key[idx] : 0ull;
        __syncthreads();
        int lim = hi - t0; if (lim > 256) lim = 256;
        for (int j = 0; j < lim; j++) cnt += (tile[j] > my) ? 1 : 0;
        __syncthreads();
    }
    if (i < N_ && cnt) atomicAdd(&rankcnt[i], cnt);
}

// ---------------- selection + prefix scan + m output (merged) ----------------
__global__ __launch_bounds__(1024) void k_scanfin(const int* __restrict__ rankcnt,
    const float* __restrict__ score, int* __restrict__ node2m, int* __restrict__ midx,
    float* __restrict__ m_out)
{
    __shared__ int ssum[1024];
    int tid = threadIdx.x;
    int start = tid * 20;
    int c = 0;
    for (int k = 0; k < 20; k++) {
        int idx = start + k;
        if (idx < N_) {
            int sel = (rankcnt[idx] < K_) ? 1 : 0;
            c += sel;
            m_out[idx] = sel ? score[idx] : 0.0f;
        }
    }
    ssum[tid] = c;
    __syncthreads();
    for (int off = 1; off < 1024; off <<= 1) {
        int v = (tid >= off) ? ssum[tid - off] : 0;
        __syncthreads();
        ssum[tid] += v;
        __syncthreads();
    }
    int run = ssum[tid] - c;
    for (int k = 0; k < 20; k++) {
        int idx = start + k;
        if (idx < N_) {
            if (rankcnt[idx] < K_) { node2m[idx] = run; midx[run] = idx; run++; }
            else node2m[idx] = -1;
        }
    }
}

// ---------------- master gather + q/k proj + exist matrix (merged) ----------------
__global__ __launch_bounds__(256) void k_mastex(const int* __restrict__ midx,
    const float* __restrict__ h_local, const float* __restrict__ pos,
    const float* __restrict__ vg_wq, const float* __restrict__ vg_wk,
    const int* __restrict__ src, const int* __restrict__ dst, const int* __restrict__ node2m,
    float* __restrict__ h_m, float* __restrict__ pos_m,
    float* __restrict__ qbuf, float* __restrict__ kbuf,
    int* __restrict__ src_all, int* __restrict__ dst_all,
    float* __restrict__ mask_all, unsigned char* __restrict__ exist)
{
    int b = blockIdx.x;
    if (b < 500) {
        int mi = b * 4 + (threadIdx.x >> 6);
        int lane = threadIdx.x & 63;
        int node = midx[mi];
        h_m[mi*64 + lane] = h_local[node*64 + lane];
        if (lane < 3) pos_m[mi*3 + lane] = pos[node*3 + lane];
        if (lane < 32) {
            int j = lane & 15;
            const float* wm = (lane < 16) ? vg_wq : vg_wk;
            float acc = 0.0f;
            #pragma unroll
            for (int i = 0; i < 16; i++) acc += h_local[node*64 + i] * wm[i*16 + j];
            if (lane < 16) qbuf[mi*16 + j] = acc; else kbuf[mi*16 + j] = acc;
        }
    } else {
        int e = (b - 500) * 256 + threadIdx.x;   // covers exactly E_
        int sm = node2m[src[e]], dm = node2m[dst[e]];
        bool em = (sm >= 0) && (dm >= 0);
        int smc = sm >= 0 ? sm : 0;
        int dmc = dm >= 0 ? dm : 0;
        src_all[e] = smc; dst_all[e] = dmc; mask_all[e] = em ? 1.0f : 0.0f;
        if (em) exist[smc * K_ + dmc] = 1;
    }
}

// ---------------- attention pass 1: Av + per-tile max + 1024-bin candidate histogram ----------------
constexpr int NTILE_ = (K_ / 16) * (K_ / 16);   // 15625
__global__ __launch_bounds__(256) void k_attn1(const float* __restrict__ qbuf,
    const float* __restrict__ kbuf, const unsigned char* __restrict__ exist,
    float* __restrict__ Av, float* __restrict__ tmax, unsigned int* __restrict__ hist)
{
    constexpr int TBK = K_ / 16;
    __shared__ float sq[16][17], sk[16][17];
    __shared__ unsigned int lh[1024];
    __shared__ float wmax[4];
    int tid = threadIdx.x;
    for (int b = tid; b < 1024; b += 256) lh[b] = 0;

    for (int t = blockIdx.x; t < NTILE_; t += gridDim.x) {
        int bi = t / TBK, bj = t % TBK;
        int i0 = bi * 16, j0 = bj * 16;
        int r = tid >> 4, c = tid & 15;
        __syncthreads();
        sq[r][c] = qbuf[(i0 + r) * 16 + c];
        sk[r][c] = kbuf[(j0 + r) * 16 + c];
        __syncthreads();
        int ti = tid >> 4, tj = tid & 15;
        float dot = 0.0f;
        #pragma unroll
        for (int cc = 0; cc < 16; cc++) dot += sq[ti][cc] * sk[tj][cc];
        float attn = 1.0f / (1.0f + expf(-dot * 0.25f));
        int gi = i0 + ti, gj = j0 + tj;
        int flat = gi * K_ + gj;
        bool ex = (exist[flat] != 0) || (gi == gj);
        bool av = (!ex) && (attn > 0.5f);
        Av[flat] = av ? 1.0f : 0.0f;
        float cv = av ? attn : 0.0f;
        if (av) {
            unsigned bin = (__float_as_uint(attn) - 0x3F000000u) >> 13;
            if (bin > 1023u) bin = 1023u;
            atomicAdd(&lh[bin], 1u);
        }
        float wm = cv;
        #pragma unroll
        for (int off = 32; off > 0; off >>= 1) wm = fmaxf(wm, __shfl_xor(wm, off));
        int wid = tid >> 6, lane = tid & 63;
        if (lane == 0) wmax[wid] = wm;
        __syncthreads();
        if (tid == 0) tmax[t] = fmaxf(fmaxf(wmax[0], wmax[1]), fmaxf(wmax[2], wmax[3]));
    }
    __syncthreads();
    for (int b = tid; b < 1024; b += 256) {
        unsigned v = lh[b];
        if (v) atomicAdd(&hist[b], v);
    }
}

// ---------------- pick bin threshold B: suffix(B) >= R = min(EV, total) ----------------
__global__ __launch_bounds__(1024) void k_bsel(const unsigned int* __restrict__ hist, RState* st)
{
    __shared__ unsigned int h[1024];
    int tid = threadIdx.x;
    h[tid] = hist[tid];
    __syncthreads();
    for (int off = 1; off < 1024; off <<= 1) {
        unsigned v = (tid + off < 1024) ? h[tid + off] : 0u;
        __syncthreads();
        h[tid] += v;
        __syncthreads();
    }
    unsigned total = h[0];
    int R = (total < (unsigned)EV_) ? (int)total : EV_;
    if (tid == 0) {
        st->R = R;
        st->total = total;
        st->cand_count = 0;
        st->sel_count = 0;
        if (R == 0) st->bin_thresh = 1024;
    }
    __syncthreads();
    if (R > 0) {
        unsigned hi = (tid == 1023) ? 0u : h[tid + 1];
        if ((int)h[tid] >= R && (int)hi < R) st->bin_thresh = tid;
    }
}

// ---------------- attention pass 2: store candidate keys above bin threshold ----------------
__global__ __launch_bounds__(256) void k_attn2(const float* __restrict__ qbuf,
    const float* __restrict__ kbuf, const unsigned char* __restrict__ exist,
    const float* __restrict__ tmax, RState* st, unsigned long long* __restrict__ cand)
{
    constexpr int TBK = K_ / 16;
    __shared__ float sq[16][17], sk[16][17];
    __shared__ int wb[4];
    __shared__ int bb;
    int tid = threadIdx.x;
    unsigned tbits = 0x3F000000u + ((unsigned)st->bin_thresh << 13);

    for (int t = blockIdx.x; t < NTILE_; t += gridDim.x) {
        if (__float_as_uint(tmax[t]) < tbits) continue;     // uniform per block
        int bi = t / TBK, bj = t % TBK;
        int i0 = bi * 16, j0 = bj * 16;
        int r = tid >> 4, c = tid & 15;
        __syncthreads();
        sq[r][c] = qbuf[(i0 + r) * 16 + c];
        sk[r][c] = kbuf[(j0 + r) * 16 + c];
        __syncthreads();
        int ti = tid >> 4, tj = tid & 15;
        float dot = 0.0f;
        #pragma unroll
        for (int cc = 0; cc < 16; cc++) dot += sq[ti][cc] * sk[tj][cc];
        float attn = 1.0f / (1.0f + expf(-dot * 0.25f));
        int gi = i0 + ti, gj = j0 + tj;
        int flat = gi * K_ + gj;
        bool ex = (exist[flat] != 0) || (gi == gj);
        bool store = (!ex) && (attn > 0.5f) && (__float_as_uint(attn) >= tbits);

        unsigned long long keyv = ((unsigned long long)__float_as_uint(attn) << 32)
                                | (unsigned long long)(0xFFFFFFFFu - (unsigned)flat);
        int wid = tid >> 6, lane = tid & 63;
        unsigned long long b = __ballot(store);
        int wc = __popcll(b);
        if (lane == 0) wb[wid] = wc;
        __syncthreads();
        if (tid == 0) {
            int s = 0;
            for (int w = 0; w < 4; w++) { int cc2 = wb[w]; wb[w] = s; s += cc2; }
            bb = s ? (int)atomicAdd(&st->cand_count, (unsigned)s) : 0;
        }
        __syncthreads();
        if (store) {
            int slot = bb + wb[wid] + __popcll(b & ((1ull << lane) - 1ull));
            cand[slot] = keyv;
        }
    }
}

// ---------------- single-block radix select + virtual-edge emit (merged) ----------------
__global__ __launch_bounds__(1024) void k_radixsel(RState* st,
    const unsigned long long* __restrict__ cand,
    int* __restrict__ src_all, int* __restrict__ dst_all, float* __restrict__ mask_all)
{
    __shared__ unsigned int lh[256];
    __shared__ unsigned int suf[256];
    __shared__ unsigned long long s_pref;
    __shared__ int s_R;
    int tid = threadIdx.x;
    int n = (int)st->cand_count;
    int R = st->R;
    if (tid == 0) { s_pref = 0ull; s_R = R; }
    __syncthreads();

    if (R > 0) {
        for (int p = 0; p < 8; p++) {
            if (tid < 256) lh[tid] = 0;
            __syncthreads();
            unsigned long long pref = s_pref;
            int sh_d = 56 - 8 * p;
            for (int i = tid; i < n; i += 1024) {
                unsigned long long kv = cand[i];
                bool ok = (p == 0) || ((kv >> (sh_d + 8)) == (pref >> (sh_d + 8)));
                if (ok) atomicAdd(&lh[(unsigned)((kv >> sh_d) & 255ull)], 1u);
            }
            __syncthreads();
            if (tid < 256) suf[tid] = lh[tid];
            __syncthreads();
            for (int off = 1; off < 256; off <<= 1) {
                unsigned v = 0;
                if (tid < 256 && tid + off < 256) v = suf[tid + off];
                __syncthreads();
                if (tid < 256) suf[tid] += v;
                __syncthreads();
            }
            if (tid < 256) {
                int Rc = s_R;
                unsigned hi = (tid == 255) ? 0u : suf[tid + 1];
                if ((int)suf[tid] >= Rc && (int)hi < Rc) {
                    s_pref = pref | ((unsigned long long)(unsigned)tid << sh_d);
                    s_R = Rc - (int)hi;
                }
            }
            __syncthreads();
        }
    } else {
        if (tid == 0) s_pref = ~0ull;
        __syncthreads();
    }

    unsigned long long T = s_pref;
    int lane = tid & 63;
    for (int i0 = 0; i0 < n; i0 += 1024) {
        int i = i0 + tid;
        bool sel = (i < n) && (cand[i] >= T);
        unsigned long long b = __ballot(sel);
        int wc = __popcll(b);
        int basep = 0;
        if (lane == 0 && wc) basep = (int)atomicAdd(&st->sel_count, (unsigned)wc);
        basep = __shfl(basep, 0);
        if (sel) {
            int slot = basep + __popcll(b & ((1ull << lane) - 1ull));
            if (slot < EV_) {
                unsigned flat = 0xFFFFFFFFu - (unsigned)(cand[i] & 0xFFFFFFFFull);
                src_all[E_ + slot] = (int)(flat / (unsigned)K_);
                dst_all[E_ + slot] = (int)(flat % (unsigned)K_);
                mask_all[E_ + slot] = 1.0f;
            }
        }
    }
}

// ---------------- final mixing + pos copy (merged) ----------------
__global__ void k_finalpos(const float* __restrict__ h_local, const int* __restrict__ node2m,
    const float* __restrict__ aggm, const float* __restrict__ degm, const float* __restrict__ h_m,
    const float* __restrict__ m_out, const float* __restrict__ pos,
    float* __restrict__ out_h, float* __restrict__ out_pos)
{
    int idx = blockIdx.x * 256 + threadIdx.x;
    if (idx < N_ * 3) out_pos[idx] = pos[idx];
    if (idx >= N_ * C_) return;
    int i = idx >> 6, c = idx & 63;
    float mval = m_out[i];
    int mi = node2m[i];
    float hh = 0.0f;
    if (mi >= 0) hh = aggm[mi*64 + c] / fmaxf(degm[mi], 1.0f) + h_m[mi*64 + c];
    out_h[idx] = (1.0f - mval) * h_local[idx] + mval * hh;
}

// ---------------- launch ----------------
extern "C" void kernel_launch(void* const* d_in, const int* in_sizes, int n_in,
                              void* d_out, int out_size, void* d_ws, size_t ws_size,
                              hipStream_t stream)
{
    (void)in_sizes; (void)n_in; (void)out_size; (void)ws_size;
    const float* h     = (const float*)d_in[0];
    const float* pos   = (const float*)d_in[1];
    const int*   eidx  = (const int*)d_in[2];
    const float* fc_w1 = (const float*)d_in[3];
    const float* fc_b1 = (const float*)d_in[4];
    const float* fc_w2 = (const float*)d_in[5];
    const float* fc_b2 = (const float*)d_in[6];
    const float* lin_w = (const float*)d_in[7];
    const float* ms_w1 = (const float*)d_in[8];
    const float* ms_b1 = (const float*)d_in[9];
    const float* ms_w2 = (const float*)d_in[10];
    const float* ms_b2 = (const float*)d_in[11];
    const float* vg_wq = (const float*)d_in[12];
    const float* vg_wk = (const float*)d_in[13];

    char* ws = (char*)d_ws;
    float* agg     = (float*)(ws + OFF_AGG);
    float* deg     = (float*)(ws + OFF_DEG);
    float* aggm    = (float*)(ws + OFF_AGGM);
    float* degm    = (float*)(ws + OFF_DEGM);
    int*   rankcnt = (int*)(ws + OFF_RANK);
    float* mask_all = (float*)(ws + OFF_MASKA);
    unsigned char* exist = (unsigned char*)(ws + OFF_EXIST);
    unsigned int* hist = (unsigned int*)(ws + OFF_HIST);
    RState* st     = (RState*)(ws + OFF_STATE);
    unsigned int* cnt0 = (unsigned int*)(ws + OFF_STATE + 64);
    unsigned int* cnt1 = (unsigned int*)(ws + OFF_STATE + 68);
    int*   w0nz    = (int*)(ws + OFF_STATE + 72);
    float* h_local = (float*)(ws + OFF_HLOCAL);
    unsigned long long* key = (unsigned long long*)(ws + OFF_KEY);
    float* score   = (float*)(ws + OFF_SCORE);
    int*   node2m  = (int*)(ws + OFF_N2M);
    int*   midx    = (int*)(ws + OFF_MIDX);
    float* h_m     = (float*)(ws + OFF_HM);
    float* pos_m   = (float*)(ws + OFF_POSM);
    float* qbuf    = (float*)(ws + OFF_Q);
    float* kbuf    = (float*)(ws + OFF_KBUF);
    int*   src_all = (int*)(ws + OFF_SRCA);
    int*   dst_all = (int*)(ws + OFF_DSTA);
    float* tmax    = (float*)(ws + OFF_TMAX);
    unsigned long long* cand = (unsigned long long*)(ws + OFF_CAND);
    float* edata   = (float*)(ws + OFF_CAND);        // overlays cand (stream-ordered: safe)

    float* out_h   = (float*)d_out;
    float* out_pos = out_h + (size_t)N_ * C_;
    float* out_av  = out_pos + (size_t)N_ * 3;
    float* out_m   = out_av + (size_t)K_ * K_;

    // single contiguous zero-init
    hipMemsetAsync(ws, 0, ZERO_BYTES, stream);

    k_w0<<<1, 576, 0, stream>>>(fc_b1, fc_w2, fc_b2, w0nz);

    // ---- conv 1 on full graph ----
    k_prep<<<E_ / 256, 256, 0, stream>>>(E_, eidx, eidx + E_, nullptr, pos, w0nz, deg, edata, cnt0);
    k_convg<<<1024, 256, 0, stream>>>(cnt0, edata, h, fc_w1, fc_b1, fc_w2, fc_b2, lin_w, agg);

    k_hlscore<<<(N_ + 3) / 4, 256, 0, stream>>>(h, agg, deg, ms_w1, ms_b1, ms_w2, ms_b2,
                                                h_local, score, key);

    k_rank<<<dim3((N_ + 255) / 256, 16), 256, 0, stream>>>(key, rankcnt);
    k_scanfin<<<1, 1024, 0, stream>>>(rankcnt, score, node2m, midx, out_m);

    k_mastex<<<500 + E_ / 256, 256, 0, stream>>>(midx, h_local, pos, vg_wq, vg_wk,
        eidx, eidx + E_, node2m, h_m, pos_m, qbuf, kbuf, src_all, dst_all, mask_all, exist);

    // ---- virtual edge selection ----
    k_attn1<<<1024, 256, 0, stream>>>(qbuf, kbuf, exist, out_av, tmax, hist);
    k_bsel<<<1, 1024, 0, stream>>>(hist, st);
    k_attn2<<<1024, 256, 0, stream>>>(qbuf, kbuf, exist, tmax, st, cand);
    k_radixsel<<<1, 1024, 0, stream>>>(st, cand, src_all, dst_all, mask_all);

    // ---- conv 2 on master graph ----
    k_prep<<<EALL_ / 256, 256, 0, stream>>>(EALL_, src_all, dst_all, mask_all, pos_m, w0nz,
                                            degm, edata, cnt1);
    k_convg<<<1024, 256, 0, stream>>>(cnt1, edata, h_m, fc_w1, fc_b1, fc_w2, fc_b2, lin_w, aggm);

    k_finalpos<<<(N_ * C_ + 255) / 256, 256, 0, stream>>>(h_local, node2m, aggm, degm, h_m,
                                                          out_m, pos, out_h, out_pos);
}